// Round 5
// baseline (20236.559 us; speedup 1.0000x reference)
//
#include <hip/hip_runtime.h>

__device__ __forceinline__ float sigm(float x) { return 1.0f / (1.0f + expf(-x)); }

__global__ void k_zero_f(float* __restrict__ p, int n) {
  int i = blockIdx.x * blockDim.x + threadIdx.x;
  if (i < n) p[i] = 0.0f;
}
__global__ void k_zero_i(int* __restrict__ p, int n) {
  int i = blockIdx.x * blockDim.x + threadIdx.x;
  if (i < n) p[i] = 0;
}

__global__ void k_cnt(const int* __restrict__ dst, int* __restrict__ cnt, int E) {
  int e = blockIdx.x * blockDim.x + threadIdx.x;
  if (e < E) atomicAdd(&cnt[dst[e]], 1);
}

// h[n,f] = relu(sum_k x[n,k] * W_node[k,f] + b_node[f])
__global__ void k_node(const float* __restrict__ x, const float* __restrict__ Wn,
                       const float* __restrict__ bn, float* __restrict__ h, int N) {
  int tid = blockIdx.x * blockDim.x + threadIdx.x;
  if (tid >= N * 64) return;
  int n = tid >> 6, f = tid & 63;
  float acc = bn[f];
  for (int k = 0; k < 8; ++k) acc += x[(size_t)n * 8 + k] * Wn[k * 64 + f];
  h[tid] = fmaxf(acc, 0.0f);
}

// hmid[e,t] = relu( sum_j relu(sum_k ea_in[e,k]*W_ea[k,j]+b_ea[j]) * W_e1[j,t] + b_e1[t] )
__global__ void k_edge_mlp(const float* __restrict__ ea_in, const float* __restrict__ Wea,
                           const float* __restrict__ bea, const float* __restrict__ We1,
                           const float* __restrict__ be1, float* __restrict__ hmid, int E) {
  int tid = blockIdx.x * blockDim.x + threadIdx.x;
  if (tid >= E * 128) return;
  int e = tid >> 7, t = tid & 127;
  const float* att = ea_in + (size_t)e * 19;
  float ea[12];
  for (int j = 0; j < 12; ++j) {
    float a = bea[j];
    for (int k = 0; k < 19; ++k) a += att[k] * Wea[k * 12 + j];
    ea[j] = fmaxf(a, 0.0f);
  }
  float a = be1[t];
  for (int j = 0; j < 12; ++j) a += ea[j] * We1[j * 128 + t];
  hmid[(size_t)e * 128 + t] = fmaxf(a, 0.0f);
}

// C[row, col] = sum_k hmid[row,k] * W_e2[k,col] + b_e2[col]   (native W_e2 layout)
__global__ void k_gemm_naive(const float* __restrict__ hmid, const float* __restrict__ W2,
                             const float* __restrict__ b2, float* __restrict__ C, int M) {
  long long tid = (long long)blockIdx.x * blockDim.x + threadIdx.x;
  if (tid >= (long long)M * 4096) return;
  int row = (int)(tid >> 12), col = (int)(tid & 4095);
  const float* a = hmid + (size_t)row * 128;
  float acc = b2[col];
  for (int k = 0; k < 128; ++k) acc += a[k] * W2[(size_t)k * 4096 + col];
  C[(size_t)row * 4096 + col] = acc;
}

// msg[e,f] = sum_d h[src[e],d] * Wedge[e,d,f];  agg[dst[e],f] += msg[e,f]
__global__ void k_msg(const float* __restrict__ Wedge, const float* __restrict__ h,
                      const int* __restrict__ src, const int* __restrict__ dst,
                      float* __restrict__ agg, int E) {
  int tid = blockIdx.x * blockDim.x + threadIdx.x;
  if (tid >= E * 64) return;
  int e = tid >> 6, f = tid & 63;
  int s = src[e];
  const float* W = Wedge + (size_t)e * 4096 + f;
  const float* hv = h + (size_t)s * 64;
  float acc = 0.0f;
  for (int d = 0; d < 64; ++d) acc += hv[d] * W[(size_t)d * 64];
  atomicAdd(&agg[(size_t)dst[e] * 64 + f], acc);
}

// m = relu(agg/cnt + conv_bias); GRU (PyTorch r,z,n order), native W_ih/W_hh [192,64] layout.
// Double-buffered: reads hin, writes hout (no in-place races by construction).
__global__ void k_gru(const float* __restrict__ agg, const int* __restrict__ cnt,
                      const float* __restrict__ cb, const float* __restrict__ Wih,
                      const float* __restrict__ bih, const float* __restrict__ Whh,
                      const float* __restrict__ bhh, const float* __restrict__ hin,
                      float* __restrict__ hout, int N) {
  int tid = blockIdx.x * blockDim.x + threadIdx.x;
  if (tid >= N * 64) return;
  int n = tid >> 6, f = tid & 63;
  float cf = fmaxf((float)cnt[n], 1.0f);
  const float* arow = agg + (size_t)n * 64;
  const float* hrow = hin + (size_t)n * 64;
  float ir = bih[f], iz = bih[64 + f], in2 = bih[128 + f];
  float hr = bhh[f], hz = bhh[64 + f], hn = bhh[128 + f];
  for (int k = 0; k < 64; ++k) {
    float mk = fmaxf(arow[k] / cf + cb[k], 0.0f);
    float hk = hrow[k];
    ir += mk * Wih[f * 64 + k];            // W_ih[f, k]
    iz += mk * Wih[(64 + f) * 64 + k];     // W_ih[64+f, k]
    in2 += mk * Wih[(128 + f) * 64 + k];   // W_ih[128+f, k]
    hr += hk * Whh[f * 64 + k];
    hz += hk * Whh[(64 + f) * 64 + k];
    hn += hk * Whh[(128 + f) * 64 + k];
  }
  float r = sigm(ir + hr);
  float z = sigm(iz + hz);
  float ng = tanhf(in2 + r * hn);
  hout[tid] = (1.0f - z) * ng + z * hrow[f];
}

// out[e] = relu([0.5*(h[a]+h[b]), ea3[e]] @ W_l1 + b_l1) @ W_l2 + b_l2
__global__ void k_final(const float* __restrict__ h, const float* __restrict__ ea3,
                        const int* __restrict__ idx3, const float* __restrict__ Wl1,
                        const float* __restrict__ bl1, const float* __restrict__ Wl2,
                        const float* __restrict__ bl2, float* __restrict__ out, int E3) {
  int e = blockIdx.x * blockDim.x + threadIdx.x;
  if (e >= E3) return;
  int a = idx3[e], b = idx3[E3 + e];
  float feat[72];
  for (int t = 0; t < 64; ++t)
    feat[t] = 0.5f * (h[(size_t)a * 64 + t] + h[(size_t)b * 64 + t]);
  for (int j = 0; j < 8; ++j) feat[64 + j] = ea3[(size_t)e * 8 + j];
  float o = bl2[0];
  for (int t = 0; t < 128; ++t) {
    float acc = bl1[t];
    for (int k = 0; k < 72; ++k) acc += feat[k] * Wl1[k * 128 + t];
    o += fmaxf(acc, 0.0f) * Wl2[t];
  }
  out[e] = o;
}

extern "C" void kernel_launch(void* const* d_in, const int* in_sizes, int n_in,
                              void* d_out, int out_size, void* d_ws, size_t ws_size,
                              hipStream_t stream) {
  const float* x          = (const float*)d_in[0];
  const float* edge_attr  = (const float*)d_in[1];
  const float* edge_attr3 = (const float*)d_in[2];
  const int*   edge_index = (const int*)d_in[3];
  const int*   edge_index3= (const int*)d_in[4];
  const float* W_node = (const float*)d_in[5];
  const float* b_node = (const float*)d_in[6];
  const float* W_ea   = (const float*)d_in[7];
  const float* b_ea   = (const float*)d_in[8];
  const float* W_e1   = (const float*)d_in[9];
  const float* b_e1   = (const float*)d_in[10];
  const float* W_e2   = (const float*)d_in[11];
  const float* b_e2   = (const float*)d_in[12];
  const float* conv_bias = (const float*)d_in[13];
  const float* W_ih   = (const float*)d_in[14];
  const float* b_ih   = (const float*)d_in[15];
  const float* W_hh   = (const float*)d_in[16];
  const float* b_hh   = (const float*)d_in[17];
  const float* W_l1   = (const float*)d_in[18];
  const float* b_l1   = (const float*)d_in[19];
  const float* W_l2   = (const float*)d_in[20];
  const float* b_l2   = (const float*)d_in[21];

  int N  = in_sizes[0] / 8;
  int E  = in_sizes[1] / 19;
  int E3 = in_sizes[2] / 8;

  char* p = (char*)d_ws;
  size_t used = 0;
  auto carve = [&](size_t bytes) -> void* {
    char* q = p;
    size_t padded = (bytes + 255) & ~(size_t)255;
    p += padded;
    used += padded;
    return (void*)q;
  };
  float* hA   = (float*)carve((size_t)N * 64 * 4);
  float* hB   = (float*)carve((size_t)N * 64 * 4);
  float* agg  = (float*)carve((size_t)N * 64 * 4);
  int*   cnt  = (int*)carve((size_t)N * 4);
  float* hmid = (float*)carve((size_t)E * 128 * 4);
  // Remaining workspace -> fp32 Wedge chunk buffer.
  size_t fixed = used;
  size_t avail = (ws_size > fixed + 256) ? (ws_size - fixed - 256) : 0;
  size_t row_bytes = 4096 * 4;
  long long rows_fit = (long long)(avail / row_bytes);
  int Ec;
  bool full = (rows_fit >= (long long)E);
  if (full) Ec = E;
  else {
    Ec = (int)((rows_fit / 64) * 64);
    if (Ec < 64) Ec = 64;
    if (Ec > E) Ec = E;
  }
  float* Wedge = (float*)carve((size_t)Ec * row_bytes);

  const int* src = edge_index;
  const int* dst = edge_index + E;

  k_zero_i<<<(N + 255) / 256, 256, 0, stream>>>(cnt, N);
  k_cnt<<<(E + 255) / 256, 256, 0, stream>>>(dst, cnt, E);
  k_node<<<((size_t)N * 64 + 255) / 256, 256, 0, stream>>>(x, W_node, b_node, hA, N);
  k_edge_mlp<<<((size_t)E * 128 + 255) / 256, 256, 0, stream>>>(edge_attr, W_ea, b_ea,
                                                                W_e1, b_e1, hmid, E);
  if (full) {
    long long tot = (long long)E * 4096;
    k_gemm_naive<<<(unsigned)((tot + 255) / 256), 256, 0, stream>>>(hmid, W_e2, b_e2, Wedge, E);
  }

  float* hcur = hA;
  float* hnxt = hB;
  for (int it = 0; it < 3; ++it) {
    k_zero_f<<<((size_t)N * 64 + 255) / 256, 256, 0, stream>>>(agg, N * 64);
    if (full) {
      k_msg<<<((size_t)E * 64 + 255) / 256, 256, 0, stream>>>(Wedge, hcur, src, dst, agg, E);
    } else {
      for (int e0 = 0; e0 < E; e0 += Ec) {
        int ec = (E - e0 < Ec) ? (E - e0) : Ec;
        long long tot = (long long)ec * 4096;
        k_gemm_naive<<<(unsigned)((tot + 255) / 256), 256, 0, stream>>>(
            hmid + (size_t)e0 * 128, W_e2, b_e2, Wedge, ec);
        k_msg<<<((size_t)ec * 64 + 255) / 256, 256, 0, stream>>>(Wedge, hcur, src + e0,
                                                                 dst + e0, agg, ec);
      }
    }
    k_gru<<<((size_t)N * 64 + 255) / 256, 256, 0, stream>>>(agg, cnt, conv_bias, W_ih, b_ih,
                                                            W_hh, b_hh, hcur, hnxt, N);
    float* tmp = hcur; hcur = hnxt; hnxt = tmp;
  }
  k_final<<<(E3 + 255) / 256, 256, 0, stream>>>(hcur, edge_attr3, edge_index3, W_l1, b_l1,
                                                W_l2, b_l2, (float*)d_out, E3);
}

// Round 6
// 4622.963 us; speedup vs baseline: 4.3774x; 4.3774x over previous
//
#include <hip/hip_runtime.h>

typedef unsigned short u16;
typedef unsigned int u32;
typedef __attribute__((ext_vector_type(8))) short short8v;
typedef __attribute__((ext_vector_type(4))) float float4v;

__device__ __forceinline__ float sigm(float x) { return 1.0f / (1.0f + expf(-x)); }
__device__ __forceinline__ u16 f2bf(float f) {
  u32 u = __float_as_uint(f);
  u32 r = (u + 0x7fffu + ((u >> 16) & 1u)) >> 16;
  return (u16)r;
}
__device__ __forceinline__ float bf2f(u16 w) { return __uint_as_float(((u32)w) << 16); }

__global__ void k_zero_f(float* __restrict__ p, int n) {
  int i = blockIdx.x * blockDim.x + threadIdx.x;
  if (i < n) p[i] = 0.0f;
}
__global__ void k_zero_i(int* __restrict__ p, int n) {
  int i = blockIdx.x * blockDim.x + threadIdx.x;
  if (i < n) p[i] = 0;
}

__global__ void k_cnt(const int* __restrict__ dst, int* __restrict__ cnt, int E) {
  int e = blockIdx.x * blockDim.x + threadIdx.x;
  if (e < E) atomicAdd(&cnt[dst[e]], 1);
}

// h[n,f] = relu(sum_k x[n,k] * W_node[k,f] + b_node[f])   [verified r5]
__global__ void k_node(const float* __restrict__ x, const float* __restrict__ Wn,
                       const float* __restrict__ bn, float* __restrict__ h, int N) {
  int tid = blockIdx.x * blockDim.x + threadIdx.x;
  if (tid >= N * 64) return;
  int n = tid >> 6, f = tid & 63;
  float acc = bn[f];
  for (int k = 0; k < 8; ++k) acc += x[(size_t)n * 8 + k] * Wn[k * 64 + f];
  h[tid] = fmaxf(acc, 0.0f);
}

// hmid = relu(relu(ea@Wea+bea)@We1+be1)   [verified r5]
__global__ void k_edge_mlp(const float* __restrict__ ea_in, const float* __restrict__ Wea,
                           const float* __restrict__ bea, const float* __restrict__ We1,
                           const float* __restrict__ be1, float* __restrict__ hmid, int E) {
  int tid = blockIdx.x * blockDim.x + threadIdx.x;
  if (tid >= E * 128) return;
  int e = tid >> 7, t = tid & 127;
  const float* att = ea_in + (size_t)e * 19;
  float ea[12];
  for (int j = 0; j < 12; ++j) {
    float a = bea[j];
    for (int k = 0; k < 19; ++k) a += att[k] * Wea[k * 12 + j];
    ea[j] = fmaxf(a, 0.0f);
  }
  float a = be1[t];
  for (int j = 0; j < 12; ++j) a += ea[j] * We1[j * 128 + t];
  hmid[(size_t)e * 128 + t] = fmaxf(a, 0.0f);
}

// split hmid (fp32, [E,128]) into bf16 hi/lo pair, same layout
__global__ void k_split_a(const float* __restrict__ hmid, u16* __restrict__ Ahi,
                          u16* __restrict__ Alo, int total) {
  int tid = blockIdx.x * blockDim.x + threadIdx.x;
  if (tid >= total) return;
  float v = hmid[tid];
  u16 hi = f2bf(v);
  Ahi[tid] = hi;
  Alo[tid] = f2bf(v - bf2f(hi));
}

// W_e2[k,n] (128x4096) -> Bhi/Blo[n,k] (4096x128) transposed bf16 split
__global__ void k_split_bT(const float* __restrict__ W2, u16* __restrict__ Bhi,
                           u16* __restrict__ Blo) {
  int tid = blockIdx.x * blockDim.x + threadIdx.x;
  if (tid >= 128 * 4096) return;
  int k = tid >> 12;    // 0..127
  int n = tid & 4095;   // 0..4095
  float v = W2[tid];    // W2[k*4096 + n]
  u16 hi = f2bf(v);
  Bhi[n * 128 + k] = hi;
  Blo[n * 128 + k] = f2bf(v - bf2f(hi));
}

// Wedge[row, col] = sum_k hmid[row,k] * W_e2[k,col] + b_e2[col], fp32 out.
// MFMA 16x16x32 bf16, split-bf16x3 accumulate (fp32-grade).
// Tile 64(M) x 64(N); K=128 staged in two halves of 64 (LDS 36.9 KB < 64 KB).
__global__ __launch_bounds__(256) void k_gemm_mfma(
    const u16* __restrict__ Ahi, const u16* __restrict__ Alo,
    const u16* __restrict__ Bhi, const u16* __restrict__ Blo,
    const float* __restrict__ bias, float* __restrict__ C, int M) {
  __shared__ __align__(16) u16 sAh[64 * 72];
  __shared__ __align__(16) u16 sAl[64 * 72];
  __shared__ __align__(16) u16 sBh[64 * 72];
  __shared__ __align__(16) u16 sBl[64 * 72];
  int m0 = blockIdx.x * 64;
  int n0 = blockIdx.y * 64;
  int tid = threadIdx.x;
  int wave = tid >> 6;   // m-strip 0..3
  int lane = tid & 63;
  int c = lane & 15;     // A row (m) / B row (n) / D col
  int q = lane >> 4;     // k-subchunk select (input) / row-quad (output)
  float4v acc[4];
#pragma unroll
  for (int nt = 0; nt < 4; ++nt) acc[nt] = (float4v){0.f, 0.f, 0.f, 0.f};

  for (int kc = 0; kc < 2; ++kc) {
    __syncthreads();  // WAR: prior reads done before re-staging
#pragma unroll
    for (int p = 0; p < 2; ++p) {
      int slot = p * 256 + tid;        // 512 slots = 64 rows x 8 segs of 8 u16
      int r = slot >> 3, s = slot & 7;
      int gr = m0 + r;
      if (gr >= M) gr = M - 1;
      int gk = kc * 64 + s * 8;
      *(uint4*)(&sAh[r * 72 + s * 8]) = *(const uint4*)(Ahi + (size_t)gr * 128 + gk);
      *(uint4*)(&sAl[r * 72 + s * 8]) = *(const uint4*)(Alo + (size_t)gr * 128 + gk);
      *(uint4*)(&sBh[r * 72 + s * 8]) = *(const uint4*)(Bhi + (size_t)(n0 + r) * 128 + gk);
      *(uint4*)(&sBl[r * 72 + s * 8]) = *(const uint4*)(Blo + (size_t)(n0 + r) * 128 + gk);
    }
    __syncthreads();
#pragma unroll
    for (int ks = 0; ks < 2; ++ks) {
      int koff = ks * 32 + q * 8;      // lane-group q covers k [q*8, q*8+8)
      short8v ah = *(const short8v*)(&sAh[(wave * 16 + c) * 72 + koff]);
      short8v al = *(const short8v*)(&sAl[(wave * 16 + c) * 72 + koff]);
#pragma unroll
      for (int nt = 0; nt < 4; ++nt) {
        short8v bh = *(const short8v*)(&sBh[(nt * 16 + c) * 72 + koff]);
        short8v bl = *(const short8v*)(&sBl[(nt * 16 + c) * 72 + koff]);
        acc[nt] = __builtin_amdgcn_mfma_f32_16x16x32_bf16(ah, bh, acc[nt], 0, 0, 0);
        acc[nt] = __builtin_amdgcn_mfma_f32_16x16x32_bf16(al, bh, acc[nt], 0, 0, 0);
        acc[nt] = __builtin_amdgcn_mfma_f32_16x16x32_bf16(ah, bl, acc[nt], 0, 0, 0);
      }
    }
  }
  // Epilogue: direct global scalar stores (D layout: col=c, row=q*4+r in each 16x16).
#pragma unroll
  for (int nt = 0; nt < 4; ++nt) {
    float bv = bias[n0 + nt * 16 + c];
#pragma unroll
    for (int r = 0; r < 4; ++r) {
      int gm = m0 + wave * 16 + q * 4 + r;
      if (gm < M) C[(size_t)gm * 4096 + n0 + nt * 16 + c] = acc[nt][r] + bv;
    }
  }
}

// msg[e,f] = sum_d h[src[e],d] * Wedge[e,d,f]; agg[dst[e],f] += msg   [verified r5]
__global__ void k_msg(const float* __restrict__ Wedge, const float* __restrict__ h,
                      const int* __restrict__ src, const int* __restrict__ dst,
                      float* __restrict__ agg, int E) {
  int tid = blockIdx.x * blockDim.x + threadIdx.x;
  if (tid >= E * 64) return;
  int e = tid >> 6, f = tid & 63;
  int s = src[e];
  const float* W = Wedge + (size_t)e * 4096 + f;
  const float* hv = h + (size_t)s * 64;
  float acc = 0.0f;
  for (int d = 0; d < 64; ++d) acc += hv[d] * W[(size_t)d * 64];
  atomicAdd(&agg[(size_t)dst[e] * 64 + f], acc);
}

// GRU, double-buffered, native weight layout   [verified r5]
__global__ void k_gru(const float* __restrict__ agg, const int* __restrict__ cnt,
                      const float* __restrict__ cb, const float* __restrict__ Wih,
                      const float* __restrict__ bih, const float* __restrict__ Whh,
                      const float* __restrict__ bhh, const float* __restrict__ hin,
                      float* __restrict__ hout, int N) {
  int tid = blockIdx.x * blockDim.x + threadIdx.x;
  if (tid >= N * 64) return;
  int n = tid >> 6, f = tid & 63;
  float cf = fmaxf((float)cnt[n], 1.0f);
  const float* arow = agg + (size_t)n * 64;
  const float* hrow = hin + (size_t)n * 64;
  float ir = bih[f], iz = bih[64 + f], in2 = bih[128 + f];
  float hr = bhh[f], hz = bhh[64 + f], hn = bhh[128 + f];
  for (int k = 0; k < 64; ++k) {
    float mk = fmaxf(arow[k] / cf + cb[k], 0.0f);
    float hk = hrow[k];
    ir += mk * Wih[f * 64 + k];
    iz += mk * Wih[(64 + f) * 64 + k];
    in2 += mk * Wih[(128 + f) * 64 + k];
    hr += hk * Whh[f * 64 + k];
    hz += hk * Whh[(64 + f) * 64 + k];
    hn += hk * Whh[(128 + f) * 64 + k];
  }
  float r = sigm(ir + hr);
  float z = sigm(iz + hz);
  float ng = tanhf(in2 + r * hn);
  hout[tid] = (1.0f - z) * ng + z * hrow[f];
}

// final MLP   [verified r5]
__global__ void k_final(const float* __restrict__ h, const float* __restrict__ ea3,
                        const int* __restrict__ idx3, const float* __restrict__ Wl1,
                        const float* __restrict__ bl1, const float* __restrict__ Wl2,
                        const float* __restrict__ bl2, float* __restrict__ out, int E3) {
  int e = blockIdx.x * blockDim.x + threadIdx.x;
  if (e >= E3) return;
  int a = idx3[e], b = idx3[E3 + e];
  float feat[72];
  for (int t = 0; t < 64; ++t)
    feat[t] = 0.5f * (h[(size_t)a * 64 + t] + h[(size_t)b * 64 + t]);
  for (int j = 0; j < 8; ++j) feat[64 + j] = ea3[(size_t)e * 8 + j];
  float o = bl2[0];
  for (int t = 0; t < 128; ++t) {
    float acc = bl1[t];
    for (int k = 0; k < 72; ++k) acc += feat[k] * Wl1[k * 128 + t];
    o += fmaxf(acc, 0.0f) * Wl2[t];
  }
  out[e] = o;
}

extern "C" void kernel_launch(void* const* d_in, const int* in_sizes, int n_in,
                              void* d_out, int out_size, void* d_ws, size_t ws_size,
                              hipStream_t stream) {
  const float* x          = (const float*)d_in[0];
  const float* edge_attr  = (const float*)d_in[1];
  const float* edge_attr3 = (const float*)d_in[2];
  const int*   edge_index = (const int*)d_in[3];
  const int*   edge_index3= (const int*)d_in[4];
  const float* W_node = (const float*)d_in[5];
  const float* b_node = (const float*)d_in[6];
  const float* W_ea   = (const float*)d_in[7];
  const float* b_ea   = (const float*)d_in[8];
  const float* W_e1   = (const float*)d_in[9];
  const float* b_e1   = (const float*)d_in[10];
  const float* W_e2   = (const float*)d_in[11];
  const float* b_e2   = (const float*)d_in[12];
  const float* conv_bias = (const float*)d_in[13];
  const float* W_ih   = (const float*)d_in[14];
  const float* b_ih   = (const float*)d_in[15];
  const float* W_hh   = (const float*)d_in[16];
  const float* b_hh   = (const float*)d_in[17];
  const float* W_l1   = (const float*)d_in[18];
  const float* b_l1   = (const float*)d_in[19];
  const float* W_l2   = (const float*)d_in[20];
  const float* b_l2   = (const float*)d_in[21];

  int N  = in_sizes[0] / 8;
  int E  = in_sizes[1] / 19;
  int E3 = in_sizes[2] / 8;

  char* p = (char*)d_ws;
  size_t used = 0;
  auto carve = [&](size_t bytes) -> void* {
    char* q = p;
    size_t padded = (bytes + 255) & ~(size_t)255;
    p += padded;
    used += padded;
    return (void*)q;
  };
  float* hA   = (float*)carve((size_t)N * 64 * 4);
  float* hB   = (float*)carve((size_t)N * 64 * 4);
  float* agg  = (float*)carve((size_t)N * 64 * 4);
  int*   cnt  = (int*)carve((size_t)N * 4);
  float* hmid = (float*)carve((size_t)E * 128 * 4);
  u16*   Ahi  = (u16*)carve((size_t)E * 128 * 2);
  u16*   Alo  = (u16*)carve((size_t)E * 128 * 2);
  u16*   Bhi  = (u16*)carve((size_t)4096 * 128 * 2);
  u16*   Blo  = (u16*)carve((size_t)4096 * 128 * 2);
  // Remaining workspace -> fp32 Wedge chunk buffer.
  size_t fixed = used;
  size_t avail = (ws_size > fixed + 256) ? (ws_size - fixed - 256) : 0;
  size_t row_bytes = 4096 * 4;
  long long rows_fit = (long long)(avail / row_bytes);
  int Ec;
  bool full = (rows_fit >= (long long)E);
  if (full) Ec = E;
  else {
    Ec = (int)((rows_fit / 64) * 64);
    if (Ec < 64) Ec = 64;
    if (Ec > E) Ec = E;
  }
  float* Wedge = (float*)carve((size_t)Ec * row_bytes);

  const int* src = edge_index;
  const int* dst = edge_index + E;

  k_zero_i<<<(N + 255) / 256, 256, 0, stream>>>(cnt, N);
  k_cnt<<<(E + 255) / 256, 256, 0, stream>>>(dst, cnt, E);
  k_node<<<((size_t)N * 64 + 255) / 256, 256, 0, stream>>>(x, W_node, b_node, hA, N);
  k_edge_mlp<<<((size_t)E * 128 + 255) / 256, 256, 0, stream>>>(edge_attr, W_ea, b_ea,
                                                                W_e1, b_e1, hmid, E);
  k_split_a<<<((size_t)E * 128 + 255) / 256, 256, 0, stream>>>(hmid, Ahi, Alo, E * 128);
  k_split_bT<<<(128 * 4096 + 255) / 256, 256, 0, stream>>>(W_e2, Bhi, Blo);

  if (full) {
    dim3 g((E + 63) / 64, 4096 / 64);
    k_gemm_mfma<<<g, 256, 0, stream>>>(Ahi, Alo, Bhi, Blo, b_e2, Wedge, E);
  }

  float* hcur = hA;
  float* hnxt = hB;
  for (int it = 0; it < 3; ++it) {
    k_zero_f<<<((size_t)N * 64 + 255) / 256, 256, 0, stream>>>(agg, N * 64);
    if (full) {
      k_msg<<<((size_t)E * 64 + 255) / 256, 256, 0, stream>>>(Wedge, hcur, src, dst, agg, E);
    } else {
      for (int e0 = 0; e0 < E; e0 += Ec) {
        int ec = (E - e0 < Ec) ? (E - e0) : Ec;
        dim3 g((ec + 63) / 64, 4096 / 64);
        k_gemm_mfma<<<g, 256, 0, stream>>>(Ahi + (size_t)e0 * 128, Alo + (size_t)e0 * 128,
                                           Bhi, Blo, b_e2, Wedge, ec);
        k_msg<<<((size_t)ec * 64 + 255) / 256, 256, 0, stream>>>(Wedge, hcur, src + e0,
                                                                 dst + e0, agg, ec);
      }
    }
    k_gru<<<((size_t)N * 64 + 255) / 256, 256, 0, stream>>>(agg, cnt, conv_bias, W_ih, b_ih,
                                                            W_hh, b_hh, hcur, hnxt, N);
    float* tmp = hcur; hcur = hnxt; hnxt = tmp;
  }
  k_final<<<(E3 + 255) / 256, 256, 0, stream>>>(hcur, edge_attr3, edge_index3, W_l1, b_l1,
                                                W_l2, b_l2, (float*)d_out, E3);
}

// Round 7
// 1780.509 us; speedup vs baseline: 11.3656x; 2.5964x over previous
//
#include <hip/hip_runtime.h>

typedef unsigned short u16;
typedef unsigned int u32;
typedef __attribute__((ext_vector_type(8))) short short8v;
typedef __attribute__((ext_vector_type(4))) float float4v;

__device__ __forceinline__ float sigm(float x) { return 1.0f / (1.0f + expf(-x)); }
__device__ __forceinline__ u16 f2bf(float f) {
  u32 u = __float_as_uint(f);
  u32 r = (u + 0x7fffu + ((u >> 16) & 1u)) >> 16;
  return (u16)r;
}
__device__ __forceinline__ float bf2f(u16 w) { return __uint_as_float(((u32)w) << 16); }

__global__ void k_zero_f(float* __restrict__ p, int n) {
  int i = blockIdx.x * blockDim.x + threadIdx.x;
  if (i < n) p[i] = 0.0f;
}
__global__ void k_zero_i(int* __restrict__ p, int n) {
  int i = blockIdx.x * blockDim.x + threadIdx.x;
  if (i < n) p[i] = 0;
}

__global__ void k_cnt(const int* __restrict__ dst, int* __restrict__ cnt, int E) {
  int e = blockIdx.x * blockDim.x + threadIdx.x;
  if (e < E) atomicAdd(&cnt[dst[e]], 1);
}

// h[n,f] = relu(sum_k x[n,k] * W_node[k,f] + b_node[f])   [verified r5/r6]
__global__ void k_node(const float* __restrict__ x, const float* __restrict__ Wn,
                       const float* __restrict__ bn, float* __restrict__ h, int N) {
  int tid = blockIdx.x * blockDim.x + threadIdx.x;
  if (tid >= N * 64) return;
  int n = tid >> 6, f = tid & 63;
  float acc = bn[f];
  for (int k = 0; k < 8; ++k) acc += x[(size_t)n * 8 + k] * Wn[k * 64 + f];
  h[tid] = fmaxf(acc, 0.0f);
}

// hmid = relu(relu(ea@Wea+bea)@We1+be1)   [verified r5/r6]
__global__ void k_edge_mlp(const float* __restrict__ ea_in, const float* __restrict__ Wea,
                           const float* __restrict__ bea, const float* __restrict__ We1,
                           const float* __restrict__ be1, float* __restrict__ hmid, int E) {
  int tid = blockIdx.x * blockDim.x + threadIdx.x;
  if (tid >= E * 128) return;
  int e = tid >> 7, t = tid & 127;
  const float* att = ea_in + (size_t)e * 19;
  float ea[12];
  for (int j = 0; j < 12; ++j) {
    float a = bea[j];
    for (int k = 0; k < 19; ++k) a += att[k] * Wea[k * 12 + j];
    ea[j] = fmaxf(a, 0.0f);
  }
  float a = be1[t];
  for (int j = 0; j < 12; ++j) a += ea[j] * We1[j * 128 + t];
  hmid[(size_t)e * 128 + t] = fmaxf(a, 0.0f);
}

// split hmid (fp32, [E,128]) into bf16 hi/lo pair   [verified r6]
__global__ void k_split_a(const float* __restrict__ hmid, u16* __restrict__ Ahi,
                          u16* __restrict__ Alo, int total) {
  int tid = blockIdx.x * blockDim.x + threadIdx.x;
  if (tid >= total) return;
  float v = hmid[tid];
  u16 hi = f2bf(v);
  Ahi[tid] = hi;
  Alo[tid] = f2bf(v - bf2f(hi));
}

// W_e2[k,n] (128x4096) -> Bhi/Blo[n,k] (4096x128) transposed bf16 split   [verified r6]
__global__ void k_split_bT(const float* __restrict__ W2, u16* __restrict__ Bhi,
                           u16* __restrict__ Blo) {
  int tid = blockIdx.x * blockDim.x + threadIdx.x;
  if (tid >= 128 * 4096) return;
  int k = tid >> 12;
  int n = tid & 4095;
  float v = W2[tid];
  u16 hi = f2bf(v);
  Bhi[n * 128 + k] = hi;
  Blo[n * 128 + k] = f2bf(v - bf2f(hi));
}

// Fresh prep: WT[k*192 + j] = W[j*64 + k]  (W is [192,64]; WT is [64,192])
__global__ void k_prep_wt(const float* __restrict__ Wih, const float* __restrict__ Whh,
                          float* __restrict__ WTih, float* __restrict__ WThh) {
  int tid = blockIdx.x * blockDim.x + threadIdx.x;
  if (tid >= 2 * 12288) return;
  int w = tid / 12288;          // 0 -> ih, 1 -> hh
  int r = tid - w * 12288;      // 0..12287
  int k = r / 192;              // 0..63
  int j = r - k * 192;          // 0..191
  const float* W = w ? Whh : Wih;
  float* WT = w ? WThh : WTih;
  WT[k * 192 + j] = W[j * 64 + k];
}

// Wedge[row,col] = sum_k hmid[row,k]*W_e2[k,col] + b_e2[col], bf16 out.
// MFMA 16x16x32 bf16, split-bf16x3 accumulate. Tile 64x64, K in two stages of 64.
__global__ __launch_bounds__(256) void k_gemm_mfma(
    const u16* __restrict__ Ahi, const u16* __restrict__ Alo,
    const u16* __restrict__ Bhi, const u16* __restrict__ Blo,
    const float* __restrict__ bias, u16* __restrict__ C, int M) {
  __shared__ __align__(16) u16 sAh[64 * 72];
  __shared__ __align__(16) u16 sAl[64 * 72];
  __shared__ __align__(16) u16 sBh[64 * 72];
  __shared__ __align__(16) u16 sBl[64 * 72];
  int m0 = blockIdx.x * 64;
  int n0 = blockIdx.y * 64;
  int tid = threadIdx.x;
  int wave = tid >> 6;
  int lane = tid & 63;
  int c = lane & 15;
  int q = lane >> 4;
  float4v acc[4];
#pragma unroll
  for (int nt = 0; nt < 4; ++nt) acc[nt] = (float4v){0.f, 0.f, 0.f, 0.f};

  for (int kc = 0; kc < 2; ++kc) {
    __syncthreads();
#pragma unroll
    for (int p = 0; p < 2; ++p) {
      int slot = p * 256 + tid;
      int r = slot >> 3, s = slot & 7;
      int gr = m0 + r;
      if (gr >= M) gr = M - 1;
      int gk = kc * 64 + s * 8;
      *(uint4*)(&sAh[r * 72 + s * 8]) = *(const uint4*)(Ahi + (size_t)gr * 128 + gk);
      *(uint4*)(&sAl[r * 72 + s * 8]) = *(const uint4*)(Alo + (size_t)gr * 128 + gk);
      *(uint4*)(&sBh[r * 72 + s * 8]) = *(const uint4*)(Bhi + (size_t)(n0 + r) * 128 + gk);
      *(uint4*)(&sBl[r * 72 + s * 8]) = *(const uint4*)(Blo + (size_t)(n0 + r) * 128 + gk);
    }
    __syncthreads();
#pragma unroll
    for (int ks = 0; ks < 2; ++ks) {
      int koff = ks * 32 + q * 8;
      short8v ah = *(const short8v*)(&sAh[(wave * 16 + c) * 72 + koff]);
      short8v al = *(const short8v*)(&sAl[(wave * 16 + c) * 72 + koff]);
#pragma unroll
      for (int nt = 0; nt < 4; ++nt) {
        short8v bh = *(const short8v*)(&sBh[(nt * 16 + c) * 72 + koff]);
        short8v bl = *(const short8v*)(&sBl[(nt * 16 + c) * 72 + koff]);
        acc[nt] = __builtin_amdgcn_mfma_f32_16x16x32_bf16(ah, bh, acc[nt], 0, 0, 0);
        acc[nt] = __builtin_amdgcn_mfma_f32_16x16x32_bf16(al, bh, acc[nt], 0, 0, 0);
        acc[nt] = __builtin_amdgcn_mfma_f32_16x16x32_bf16(ah, bl, acc[nt], 0, 0, 0);
      }
    }
  }
#pragma unroll
  for (int nt = 0; nt < 4; ++nt) {
    float bv = bias[n0 + nt * 16 + c];
#pragma unroll
    for (int r = 0; r < 4; ++r) {
      int gm = m0 + wave * 16 + q * 4 + r;
      if (gm < M) C[(size_t)gm * 4096 + n0 + nt * 16 + c] = f2bf(acc[nt][r] + bv);
    }
  }
}

// msg[e,f] = sum_d h[src[e],d] * Wedge[e,d,f]; agg[dst[e],f] += msg   (bf16 Wedge)
// One wave per edge: lane = f; Wedge reads coalesced (128 B/step), h broadcast.
__global__ void k_msg(const u16* __restrict__ Wedge, const float* __restrict__ h,
                      const int* __restrict__ src, const int* __restrict__ dst,
                      float* __restrict__ agg, int E) {
  int tid = blockIdx.x * blockDim.x + threadIdx.x;
  if (tid >= E * 64) return;
  int e = tid >> 6, f = tid & 63;
  int s = src[e];
  const u16* W = Wedge + (size_t)e * 4096 + f;
  const float* hv = h + (size_t)s * 64;
  float acc = 0.0f;
  for (int d = 0; d < 64; ++d) acc += hv[d] * bf2f(W[(size_t)d * 64]);
  atomicAdd(&agg[(size_t)dst[e] * 64 + f], acc);
}

// GRU: wave-per-node, shuffle-broadcast m/h, coalesced transposed-weight reads.
// No LDS, no barriers. Double-buffered hin/hout.
__global__ __launch_bounds__(256) void k_gru(
    const float* __restrict__ agg, const int* __restrict__ cnt,
    const float* __restrict__ cb, const float* __restrict__ WTih,
    const float* __restrict__ WThh, const float* __restrict__ bih,
    const float* __restrict__ bhh, const float* __restrict__ hin,
    float* __restrict__ hout, int N) {
  int tid = blockIdx.x * blockDim.x + threadIdx.x;
  if (tid >= N * 64) return;
  int n = tid >> 6, f = tid & 63;
  float cf = fmaxf((float)cnt[n], 1.0f);
  float m = fmaxf(agg[(size_t)n * 64 + f] / cf + cb[f], 0.0f);
  float hv = hin[(size_t)n * 64 + f];
  float ir = bih[f], iz = bih[64 + f], in2 = bih[128 + f];
  float hr = bhh[f], hz = bhh[64 + f], hn = bhh[128 + f];
#pragma unroll 4
  for (int k = 0; k < 64; ++k) {
    float mk = __shfl(m, k);   // m[k] of this node (width 64)
    float hk = __shfl(hv, k);  // h[k]
    const float* wi = WTih + k * 192;
    const float* wh = WThh + k * 192;
    ir += mk * wi[f];
    iz += mk * wi[64 + f];
    in2 += mk * wi[128 + f];
    hr += hk * wh[f];
    hz += hk * wh[64 + f];
    hn += hk * wh[128 + f];
  }
  float r = sigm(ir + hr);
  float z = sigm(iz + hz);
  float ng = tanhf(in2 + r * hn);
  hout[tid] = (1.0f - z) * ng + z * hv;
}

// final MLP   [verified r5/r6]
__global__ void k_final(const float* __restrict__ h, const float* __restrict__ ea3,
                        const int* __restrict__ idx3, const float* __restrict__ Wl1,
                        const float* __restrict__ bl1, const float* __restrict__ Wl2,
                        const float* __restrict__ bl2, float* __restrict__ out, int E3) {
  int e = blockIdx.x * blockDim.x + threadIdx.x;
  if (e >= E3) return;
  int a = idx3[e], b = idx3[E3 + e];
  float feat[72];
  for (int t = 0; t < 64; ++t)
    feat[t] = 0.5f * (h[(size_t)a * 64 + t] + h[(size_t)b * 64 + t]);
  for (int j = 0; j < 8; ++j) feat[64 + j] = ea3[(size_t)e * 8 + j];
  float o = bl2[0];
  for (int t = 0; t < 128; ++t) {
    float acc = bl1[t];
    for (int k = 0; k < 72; ++k) acc += feat[k] * Wl1[k * 128 + t];
    o += fmaxf(acc, 0.0f) * Wl2[t];
  }
  out[e] = o;
}

extern "C" void kernel_launch(void* const* d_in, const int* in_sizes, int n_in,
                              void* d_out, int out_size, void* d_ws, size_t ws_size,
                              hipStream_t stream) {
  const float* x          = (const float*)d_in[0];
  const float* edge_attr  = (const float*)d_in[1];
  const float* edge_attr3 = (const float*)d_in[2];
  const int*   edge_index = (const int*)d_in[3];
  const int*   edge_index3= (const int*)d_in[4];
  const float* W_node = (const float*)d_in[5];
  const float* b_node = (const float*)d_in[6];
  const float* W_ea   = (const float*)d_in[7];
  const float* b_ea   = (const float*)d_in[8];
  const float* W_e1   = (const float*)d_in[9];
  const float* b_e1   = (const float*)d_in[10];
  const float* W_e2   = (const float*)d_in[11];
  const float* b_e2   = (const float*)d_in[12];
  const float* conv_bias = (const float*)d_in[13];
  const float* W_ih   = (const float*)d_in[14];
  const float* b_ih   = (const float*)d_in[15];
  const float* W_hh   = (const float*)d_in[16];
  const float* b_hh   = (const float*)d_in[17];
  const float* W_l1   = (const float*)d_in[18];
  const float* b_l1   = (const float*)d_in[19];
  const float* W_l2   = (const float*)d_in[20];
  const float* b_l2   = (const float*)d_in[21];

  int N  = in_sizes[0] / 8;
  int E  = in_sizes[1] / 19;
  int E3 = in_sizes[2] / 8;

  char* p = (char*)d_ws;
  size_t used = 0;
  auto carve = [&](size_t bytes) -> void* {
    char* q = p;
    size_t padded = (bytes + 255) & ~(size_t)255;
    p += padded;
    used += padded;
    return (void*)q;
  };
  float* hA   = (float*)carve((size_t)N * 64 * 4);
  float* hB   = (float*)carve((size_t)N * 64 * 4);
  float* agg  = (float*)carve((size_t)N * 64 * 4);
  int*   cnt  = (int*)carve((size_t)N * 4);
  float* hmid = (float*)carve((size_t)E * 128 * 4);
  u16*   Ahi  = (u16*)carve((size_t)E * 128 * 2);
  u16*   Alo  = (u16*)carve((size_t)E * 128 * 2);
  u16*   Bhi  = (u16*)carve((size_t)4096 * 128 * 2);
  u16*   Blo  = (u16*)carve((size_t)4096 * 128 * 2);
  float* WTih = (float*)carve(12288 * 4);
  float* WThh = (float*)carve(12288 * 4);
  // Remaining workspace -> bf16 Wedge chunk buffer.
  size_t fixed = used;
  size_t avail = (ws_size > fixed + 256) ? (ws_size - fixed - 256) : 0;
  size_t row_bytes = 4096 * 2;
  long long rows_fit = (long long)(avail / row_bytes);
  int Ec;
  bool full = (rows_fit >= (long long)E);
  if (full) Ec = E;
  else {
    Ec = (int)((rows_fit / 64) * 64);
    if (Ec < 64) Ec = 64;
    if (Ec > E) Ec = E;
  }
  u16* Wedge = (u16*)carve((size_t)Ec * row_bytes);

  const int* src = edge_index;
  const int* dst = edge_index + E;

  k_zero_i<<<(N + 255) / 256, 256, 0, stream>>>(cnt, N);
  k_cnt<<<(E + 255) / 256, 256, 0, stream>>>(dst, cnt, E);
  k_node<<<((size_t)N * 64 + 255) / 256, 256, 0, stream>>>(x, W_node, b_node, hA, N);
  k_edge_mlp<<<((size_t)E * 128 + 255) / 256, 256, 0, stream>>>(edge_attr, W_ea, b_ea,
                                                                W_e1, b_e1, hmid, E);
  k_split_a<<<((size_t)E * 128 + 255) / 256, 256, 0, stream>>>(hmid, Ahi, Alo, E * 128);
  k_split_bT<<<(128 * 4096 + 255) / 256, 256, 0, stream>>>(W_e2, Bhi, Blo);
  k_prep_wt<<<(2 * 12288 + 255) / 256, 256, 0, stream>>>(W_ih, W_hh, WTih, WThh);

  if (full) {
    dim3 g((E + 63) / 64, 4096 / 64);
    k_gemm_mfma<<<g, 256, 0, stream>>>(Ahi, Alo, Bhi, Blo, b_e2, Wedge, E);
  }

  float* hcur = hA;
  float* hnxt = hB;
  for (int it = 0; it < 3; ++it) {
    k_zero_f<<<((size_t)N * 64 + 255) / 256, 256, 0, stream>>>(agg, N * 64);
    if (full) {
      k_msg<<<((size_t)E * 64 + 255) / 256, 256, 0, stream>>>(Wedge, hcur, src, dst, agg, E);
    } else {
      for (int e0 = 0; e0 < E; e0 += Ec) {
        int ec = (E - e0 < Ec) ? (E - e0) : Ec;
        dim3 g((ec + 63) / 64, 4096 / 64);
        k_gemm_mfma<<<g, 256, 0, stream>>>(Ahi + (size_t)e0 * 128, Alo + (size_t)e0 * 128,
                                           Bhi, Blo, b_e2, Wedge, ec);
        k_msg<<<((size_t)ec * 64 + 255) / 256, 256, 0, stream>>>(Wedge, hcur, src + e0,
                                                                 dst + e0, agg, ec);
      }
    }
    k_gru<<<((size_t)N * 64 + 255) / 256, 256, 0, stream>>>(agg, cnt, conv_bias, WTih, WThh,
                                                            b_ih, b_hh, hcur, hnxt, N);
    float* tmp = hcur; hcur = hnxt; hnxt = tmp;
  }
  k_final<<<(E3 + 255) / 256, 256, 0, stream>>>(hcur, edge_attr3, edge_index3, W_l1, b_l1,
                                                W_l2, b_l2, (float*)d_out, E3);
}

// Round 8
// 1448.972 us; speedup vs baseline: 13.9662x; 1.2288x over previous
//
#include <hip/hip_runtime.h>

typedef unsigned short u16;
typedef unsigned int u32;
typedef __attribute__((ext_vector_type(8))) short short8v;
typedef __attribute__((ext_vector_type(4))) float float4v;

__device__ __forceinline__ float sigm(float x) { return 1.0f / (1.0f + expf(-x)); }
__device__ __forceinline__ u16 f2bf(float f) {
  u32 u = __float_as_uint(f);
  u32 r = (u + 0x7fffu + ((u >> 16) & 1u)) >> 16;
  return (u16)r;
}
__device__ __forceinline__ float bf2f(u16 w) { return __uint_as_float(((u32)w) << 16); }

__global__ void k_zero_f(float* __restrict__ p, int n) {
  int i = blockIdx.x * blockDim.x + threadIdx.x;
  if (i < n) p[i] = 0.0f;
}
__global__ void k_zero_i(int* __restrict__ p, int n) {
  int i = blockIdx.x * blockDim.x + threadIdx.x;
  if (i < n) p[i] = 0;
}

__global__ void k_cnt(const int* __restrict__ dst, int* __restrict__ cnt, int E) {
  int e = blockIdx.x * blockDim.x + threadIdx.x;
  if (e < E) atomicAdd(&cnt[dst[e]], 1);
}

// h[n,f] = relu(sum_k x[n,k] * W_node[k,f] + b_node[f])   [verified r5-r7]
__global__ void k_node(const float* __restrict__ x, const float* __restrict__ Wn,
                       const float* __restrict__ bn, float* __restrict__ h, int N) {
  int tid = blockIdx.x * blockDim.x + threadIdx.x;
  if (tid >= N * 64) return;
  int n = tid >> 6, f = tid & 63;
  float acc = bn[f];
  for (int k = 0; k < 8; ++k) acc += x[(size_t)n * 8 + k] * Wn[k * 64 + f];
  h[tid] = fmaxf(acc, 0.0f);
}

// hmid = relu(relu(ea@Wea+bea)@We1+be1), fused bf16 hi/lo split output
// (same math as verified r5-r7 edge_mlp + r6/r7 split_a, merged store)
__global__ void k_edge_mlp(const float* __restrict__ ea_in, const float* __restrict__ Wea,
                           const float* __restrict__ bea, const float* __restrict__ We1,
                           const float* __restrict__ be1, u16* __restrict__ Ahi,
                           u16* __restrict__ Alo, int E) {
  int tid = blockIdx.x * blockDim.x + threadIdx.x;
  if (tid >= E * 128) return;
  int e = tid >> 7, t = tid & 127;
  const float* att = ea_in + (size_t)e * 19;
  float ea[12];
  for (int j = 0; j < 12; ++j) {
    float a = bea[j];
    for (int k = 0; k < 19; ++k) a += att[k] * Wea[k * 12 + j];
    ea[j] = fmaxf(a, 0.0f);
  }
  float a = be1[t];
  for (int j = 0; j < 12; ++j) a += ea[j] * We1[j * 128 + t];
  float v = fmaxf(a, 0.0f);
  u16 hi = f2bf(v);
  Ahi[tid] = hi;
  Alo[tid] = f2bf(v - bf2f(hi));
}

// W_e2[k,n] (128x4096) -> Bhi/Blo[n,k] (4096x128) transposed bf16 split   [verified r6/r7]
__global__ void k_split_bT(const float* __restrict__ W2, u16* __restrict__ Bhi,
                           u16* __restrict__ Blo) {
  int tid = blockIdx.x * blockDim.x + threadIdx.x;
  if (tid >= 128 * 4096) return;
  int k = tid >> 12;
  int n = tid & 4095;
  float v = W2[tid];
  u16 hi = f2bf(v);
  Bhi[n * 128 + k] = hi;
  Blo[n * 128 + k] = f2bf(v - bf2f(hi));
}

// WT[k*192 + j] = W[j*64 + k]   [verified r7]
__global__ void k_prep_wt(const float* __restrict__ Wih, const float* __restrict__ Whh,
                          float* __restrict__ WTih, float* __restrict__ WThh) {
  int tid = blockIdx.x * blockDim.x + threadIdx.x;
  if (tid >= 2 * 12288) return;
  int w = tid / 12288;
  int r = tid - w * 12288;
  int k = r / 192;
  int j = r - k * 192;
  const float* W = w ? Whh : Wih;
  float* WT = w ? WThh : WTih;
  WT[k * 192 + j] = W[j * 64 + k];
}

// Wedge[row,col] = sum_k hmid[row,k]*W_e2[k,col] + b_e2[col], bf16 out.
// MFMA 16x16x32 bf16, split-bf16x3 accumulate. Tile 64x64, K in two stages of 64.
// Epilogue: LDS repack -> uint4 stores (full 128B line coverage, no RFO fetches).
__global__ __launch_bounds__(256) void k_gemm_mfma(
    const u16* __restrict__ Ahi, const u16* __restrict__ Alo,
    const u16* __restrict__ Bhi, const u16* __restrict__ Blo,
    const float* __restrict__ bias, u16* __restrict__ C, int M) {
  __shared__ __align__(16) u16 sAh[64 * 72];
  __shared__ __align__(16) u16 sAl[64 * 72];
  __shared__ __align__(16) u16 sBh[64 * 72];
  __shared__ __align__(16) u16 sBl[64 * 72];
  int m0 = blockIdx.x * 64;
  int n0 = blockIdx.y * 64;
  int tid = threadIdx.x;
  int wave = tid >> 6;
  int lane = tid & 63;
  int c = lane & 15;
  int q = lane >> 4;
  float4v acc[4];
#pragma unroll
  for (int nt = 0; nt < 4; ++nt) acc[nt] = (float4v){0.f, 0.f, 0.f, 0.f};

  for (int kc = 0; kc < 2; ++kc) {
    __syncthreads();
#pragma unroll
    for (int p = 0; p < 2; ++p) {
      int slot = p * 256 + tid;
      int r = slot >> 3, s = slot & 7;
      int gr = m0 + r;
      if (gr >= M) gr = M - 1;
      int gk = kc * 64 + s * 8;
      *(uint4*)(&sAh[r * 72 + s * 8]) = *(const uint4*)(Ahi + (size_t)gr * 128 + gk);
      *(uint4*)(&sAl[r * 72 + s * 8]) = *(const uint4*)(Alo + (size_t)gr * 128 + gk);
      *(uint4*)(&sBh[r * 72 + s * 8]) = *(const uint4*)(Bhi + (size_t)(n0 + r) * 128 + gk);
      *(uint4*)(&sBl[r * 72 + s * 8]) = *(const uint4*)(Blo + (size_t)(n0 + r) * 128 + gk);
    }
    __syncthreads();
#pragma unroll
    for (int ks = 0; ks < 2; ++ks) {
      int koff = ks * 32 + q * 8;
      short8v ah = *(const short8v*)(&sAh[(wave * 16 + c) * 72 + koff]);
      short8v al = *(const short8v*)(&sAl[(wave * 16 + c) * 72 + koff]);
#pragma unroll
      for (int nt = 0; nt < 4; ++nt) {
        short8v bh = *(const short8v*)(&sBh[(nt * 16 + c) * 72 + koff]);
        short8v bl = *(const short8v*)(&sBl[(nt * 16 + c) * 72 + koff]);
        acc[nt] = __builtin_amdgcn_mfma_f32_16x16x32_bf16(ah, bh, acc[nt], 0, 0, 0);
        acc[nt] = __builtin_amdgcn_mfma_f32_16x16x32_bf16(al, bh, acc[nt], 0, 0, 0);
        acc[nt] = __builtin_amdgcn_mfma_f32_16x16x32_bf16(ah, bl, acc[nt], 0, 0, 0);
      }
    }
  }
  // Epilogue: bias + bf16 round into LDS (reuse sAh region), then coalesced stores.
  __syncthreads();  // all compute reads of sAh done before overwrite
  u16* Ct = sAh;    // [64][72] stride, only [64][64] used
#pragma unroll
  for (int nt = 0; nt < 4; ++nt) {
    float bv = bias[n0 + nt * 16 + c];
#pragma unroll
    for (int r = 0; r < 4; ++r) {
      // D layout: row = q*4 + r, col = c within each 16x16 tile
      Ct[(wave * 16 + q * 4 + r) * 72 + nt * 16 + c] = f2bf(acc[nt][r] + bv);
    }
  }
  __syncthreads();
#pragma unroll
  for (int p = 0; p < 2; ++p) {
    int slot = p * 256 + tid;  // 512 slots = 64 rows x 8 uint4 segs
    int row = slot >> 3, seg = slot & 7;
    int gm = m0 + row;
    if (gm < M)
      *(uint4*)(C + (size_t)gm * 4096 + n0 + seg * 8) = *(const uint4*)(&Ct[row * 72 + seg * 8]);
  }
}

// msg[e,f] = sum_d h[src[e],d] * bf16Wedge[e,d,f]; agg[dst[e],f] += msg   [verified r7]
__global__ void k_msg(const u16* __restrict__ Wedge, const float* __restrict__ h,
                      const int* __restrict__ src, const int* __restrict__ dst,
                      float* __restrict__ agg, int E) {
  int tid = blockIdx.x * blockDim.x + threadIdx.x;
  if (tid >= E * 64) return;
  int e = tid >> 6, f = tid & 63;
  int s = src[e];
  const u16* W = Wedge + (size_t)e * 4096 + f;
  const float* hv = h + (size_t)s * 64;
  float acc = 0.0f;
  for (int d = 0; d < 64; ++d) acc += hv[d] * bf2f(W[(size_t)d * 64]);
  atomicAdd(&agg[(size_t)dst[e] * 64 + f], acc);
}

// GRU: wave-per-node, shuffle-broadcast, coalesced transposed weights   [verified r7]
__global__ __launch_bounds__(256) void k_gru(
    const float* __restrict__ agg, const int* __restrict__ cnt,
    const float* __restrict__ cb, const float* __restrict__ WTih,
    const float* __restrict__ WThh, const float* __restrict__ bih,
    const float* __restrict__ bhh, const float* __restrict__ hin,
    float* __restrict__ hout, int N) {
  int tid = blockIdx.x * blockDim.x + threadIdx.x;
  if (tid >= N * 64) return;
  int n = tid >> 6, f = tid & 63;
  float cf = fmaxf((float)cnt[n], 1.0f);
  float m = fmaxf(agg[(size_t)n * 64 + f] / cf + cb[f], 0.0f);
  float hv = hin[(size_t)n * 64 + f];
  float ir = bih[f], iz = bih[64 + f], in2 = bih[128 + f];
  float hr = bhh[f], hz = bhh[64 + f], hn = bhh[128 + f];
#pragma unroll 4
  for (int k = 0; k < 64; ++k) {
    float mk = __shfl(m, k);
    float hk = __shfl(hv, k);
    const float* wi = WTih + k * 192;
    const float* wh = WThh + k * 192;
    ir += mk * wi[f];
    iz += mk * wi[64 + f];
    in2 += mk * wi[128 + f];
    hr += hk * wh[f];
    hz += hk * wh[64 + f];
    hn += hk * wh[128 + f];
  }
  float r = sigm(ir + hr);
  float z = sigm(iz + hz);
  float ng = tanhf(in2 + r * hn);
  hout[tid] = (1.0f - z) * ng + z * hv;
}

// final MLP   [verified r5-r7]
__global__ void k_final(const float* __restrict__ h, const float* __restrict__ ea3,
                        const int* __restrict__ idx3, const float* __restrict__ Wl1,
                        const float* __restrict__ bl1, const float* __restrict__ Wl2,
                        const float* __restrict__ bl2, float* __restrict__ out, int E3) {
  int e = blockIdx.x * blockDim.x + threadIdx.x;
  if (e >= E3) return;
  int a = idx3[e], b = idx3[E3 + e];
  float feat[72];
  for (int t = 0; t < 64; ++t)
    feat[t] = 0.5f * (h[(size_t)a * 64 + t] + h[(size_t)b * 64 + t]);
  for (int j = 0; j < 8; ++j) feat[64 + j] = ea3[(size_t)e * 8 + j];
  float o = bl2[0];
  for (int t = 0; t < 128; ++t) {
    float acc = bl1[t];
    for (int k = 0; k < 72; ++k) acc += feat[k] * Wl1[k * 128 + t];
    o += fmaxf(acc, 0.0f) * Wl2[t];
  }
  out[e] = o;
}

extern "C" void kernel_launch(void* const* d_in, const int* in_sizes, int n_in,
                              void* d_out, int out_size, void* d_ws, size_t ws_size,
                              hipStream_t stream) {
  const float* x          = (const float*)d_in[0];
  const float* edge_attr  = (const float*)d_in[1];
  const float* edge_attr3 = (const float*)d_in[2];
  const int*   edge_index = (const int*)d_in[3];
  const int*   edge_index3= (const int*)d_in[4];
  const float* W_node = (const float*)d_in[5];
  const float* b_node = (const float*)d_in[6];
  const float* W_ea   = (const float*)d_in[7];
  const float* b_ea   = (const float*)d_in[8];
  const float* W_e1   = (const float*)d_in[9];
  const float* b_e1   = (const float*)d_in[10];
  const float* W_e2   = (const float*)d_in[11];
  const float* b_e2   = (const float*)d_in[12];
  const float* conv_bias = (const float*)d_in[13];
  const float* W_ih   = (const float*)d_in[14];
  const float* b_ih   = (const float*)d_in[15];
  const float* W_hh   = (const float*)d_in[16];
  const float* b_hh   = (const float*)d_in[17];
  const float* W_l1   = (const float*)d_in[18];
  const float* b_l1   = (const float*)d_in[19];
  const float* W_l2   = (const float*)d_in[20];
  const float* b_l2   = (const float*)d_in[21];

  int N  = in_sizes[0] / 8;
  int E  = in_sizes[1] / 19;
  int E3 = in_sizes[2] / 8;

  char* p = (char*)d_ws;
  size_t used = 0;
  auto carve = [&](size_t bytes) -> void* {
    char* q = p;
    size_t padded = (bytes + 255) & ~(size_t)255;
    p += padded;
    used += padded;
    return (void*)q;
  };
  float* hA   = (float*)carve((size_t)N * 64 * 4);
  float* hB   = (float*)carve((size_t)N * 64 * 4);
  float* agg  = (float*)carve((size_t)N * 64 * 4);
  int*   cnt  = (int*)carve((size_t)N * 4);
  u16*   Ahi  = (u16*)carve((size_t)E * 128 * 2);
  u16*   Alo  = (u16*)carve((size_t)E * 128 * 2);
  u16*   Bhi  = (u16*)carve((size_t)4096 * 128 * 2);
  u16*   Blo  = (u16*)carve((size_t)4096 * 128 * 2);
  float* WTih = (float*)carve(12288 * 4);
  float* WThh = (float*)carve(12288 * 4);
  // Remaining workspace -> bf16 Wedge chunk buffer.
  size_t fixed = used;
  size_t avail = (ws_size > fixed + 256) ? (ws_size - fixed - 256) : 0;
  size_t row_bytes = 4096 * 2;
  long long rows_fit = (long long)(avail / row_bytes);
  int Ec;
  bool full = (rows_fit >= (long long)E);
  if (full) Ec = E;
  else {
    Ec = (int)((rows_fit / 64) * 64);
    if (Ec < 64) Ec = 64;
    if (Ec > E) Ec = E;
  }
  u16* Wedge = (u16*)carve((size_t)Ec * row_bytes);

  const int* src = edge_index;
  const int* dst = edge_index + E;

  k_zero_i<<<(N + 255) / 256, 256, 0, stream>>>(cnt, N);
  k_cnt<<<(E + 255) / 256, 256, 0, stream>>>(dst, cnt, E);
  k_node<<<((size_t)N * 64 + 255) / 256, 256, 0, stream>>>(x, W_node, b_node, hA, N);
  k_edge_mlp<<<((size_t)E * 128 + 255) / 256, 256, 0, stream>>>(edge_attr, W_ea, b_ea,
                                                                W_e1, b_e1, Ahi, Alo, E);
  k_split_bT<<<(128 * 4096 + 255) / 256, 256, 0, stream>>>(W_e2, Bhi, Blo);
  k_prep_wt<<<(2 * 12288 + 255) / 256, 256, 0, stream>>>(W_ih, W_hh, WTih, WThh);

  if (full) {
    dim3 g((E + 63) / 64, 4096 / 64);
    k_gemm_mfma<<<g, 256, 0, stream>>>(Ahi, Alo, Bhi, Blo, b_e2, Wedge, E);
  }

  float* hcur = hA;
  float* hnxt = hB;
  for (int it = 0; it < 3; ++it) {
    k_zero_f<<<((size_t)N * 64 + 255) / 256, 256, 0, stream>>>(agg, N * 64);
    if (full) {
      k_msg<<<((size_t)E * 64 + 255) / 256, 256, 0, stream>>>(Wedge, hcur, src, dst, agg, E);
    } else {
      for (int e0 = 0; e0 < E; e0 += Ec) {
        int ec = (E - e0 < Ec) ? (E - e0) : Ec;
        dim3 g((ec + 63) / 64, 4096 / 64);
        k_gemm_mfma<<<g, 256, 0, stream>>>(Ahi + (size_t)e0 * 128, Alo + (size_t)e0 * 128,
                                           Bhi, Blo, b_e2, Wedge, ec);
        k_msg<<<((size_t)ec * 64 + 255) / 256, 256, 0, stream>>>(Wedge, hcur, src + e0,
                                                                 dst + e0, agg, ec);
      }
    }
    k_gru<<<((size_t)N * 64 + 255) / 256, 256, 0, stream>>>(agg, cnt, conv_bias, WTih, WThh,
                                                            b_ih, b_hh, hcur, hnxt, N);
    float* tmp = hcur; hcur = hnxt; hnxt = tmp;
  }
  k_final<<<(E3 + 255) / 256, 256, 0, stream>>>(hcur, edge_attr3, edge_index3, W_l1, b_l1,
                                                W_l2, b_l2, (float*)d_out, E3);
}

// Round 9
// 1321.548 us; speedup vs baseline: 15.3128x; 1.0964x over previous
//
#include <hip/hip_runtime.h>

typedef unsigned short u16;
typedef unsigned int u32;
typedef __attribute__((ext_vector_type(8))) short short8v;
typedef __attribute__((ext_vector_type(4))) float float4v;

__device__ __forceinline__ float sigm(float x) { return 1.0f / (1.0f + expf(-x)); }
__device__ __forceinline__ u16 f2bf(float f) {
  u32 u = __float_as_uint(f);
  u32 r = (u + 0x7fffu + ((u >> 16) & 1u)) >> 16;
  return (u16)r;
}
__device__ __forceinline__ float bf2f(u16 w) { return __uint_as_float(((u32)w) << 16); }

__global__ void k_zero_f(float* __restrict__ p, int n) {
  int i = blockIdx.x * blockDim.x + threadIdx.x;
  if (i < n) p[i] = 0.0f;
}
__global__ void k_zero_i(int* __restrict__ p, int n) {
  int i = blockIdx.x * blockDim.x + threadIdx.x;
  if (i < n) p[i] = 0;
}

__global__ void k_cnt(const int* __restrict__ dst, int* __restrict__ cnt, int E) {
  int e = blockIdx.x * blockDim.x + threadIdx.x;
  if (e < E) atomicAdd(&cnt[dst[e]], 1);
}

// h[n,f] = relu(sum_k x[n,k] * W_node[k,f] + b_node[f])   [verified r5-r8]
__global__ void k_node(const float* __restrict__ x, const float* __restrict__ Wn,
                       const float* __restrict__ bn, float* __restrict__ h, int N) {
  int tid = blockIdx.x * blockDim.x + threadIdx.x;
  if (tid >= N * 64) return;
  int n = tid >> 6, f = tid & 63;
  float acc = bn[f];
  for (int k = 0; k < 8; ++k) acc += x[(size_t)n * 8 + k] * Wn[k * 64 + f];
  h[tid] = fmaxf(acc, 0.0f);
}

// hmid = relu(relu(ea@Wea+bea)@We1+be1), fused bf16 hi/lo split output   [verified r8]
__global__ void k_edge_mlp(const float* __restrict__ ea_in, const float* __restrict__ Wea,
                           const float* __restrict__ bea, const float* __restrict__ We1,
                           const float* __restrict__ be1, u16* __restrict__ Ahi,
                           u16* __restrict__ Alo, int E) {
  int tid = blockIdx.x * blockDim.x + threadIdx.x;
  if (tid >= E * 128) return;
  int e = tid >> 7, t = tid & 127;
  const float* att = ea_in + (size_t)e * 19;
  float ea[12];
  for (int j = 0; j < 12; ++j) {
    float a = bea[j];
    for (int k = 0; k < 19; ++k) a += att[k] * Wea[k * 12 + j];
    ea[j] = fmaxf(a, 0.0f);
  }
  float a = be1[t];
  for (int j = 0; j < 12; ++j) a += ea[j] * We1[j * 128 + t];
  float v = fmaxf(a, 0.0f);
  u16 hi = f2bf(v);
  Ahi[tid] = hi;
  Alo[tid] = f2bf(v - bf2f(hi));
}

// Pack W_e2 into MFMA-fragment-ordered bf16 hi/lo:
// Bp[(((d*4+ks)*4+nt)*64 + lane)*8 + j] = split(W_e2[k][n]),
//   k = ks*32 + (lane>>4)*8 + j,  n = d*64 + nt*16 + (lane&15)
// Matches the r6-r8-verified B-fragment read: B row n = nt*16+c, k-off ks*32+q*8.
__global__ void k_pack_b(const float* __restrict__ W2, u16* __restrict__ Bph,
                         u16* __restrict__ Bpl) {
  int tid = blockIdx.x * blockDim.x + threadIdx.x;
  if (tid >= 128 * 4096) return;
  int j = tid & 7;
  int lane = (tid >> 3) & 63;
  int nt = (tid >> 9) & 3;
  int ks = (tid >> 11) & 3;
  int d = tid >> 13;               // 0..63
  int c = lane & 15, q = lane >> 4;
  int k = ks * 32 + q * 8 + j;
  int n = d * 64 + nt * 16 + c;
  float v = W2[(size_t)k * 4096 + n];
  u16 hi = f2bf(v);
  Bph[tid] = hi;
  Bpl[tid] = f2bf(v - bf2f(hi));
}

// WT[k*192 + j] = W[j*64 + k]   [verified r7/r8]
__global__ void k_prep_wt(const float* __restrict__ Wih, const float* __restrict__ Whh,
                          float* __restrict__ WTih, float* __restrict__ WThh) {
  int tid = blockIdx.x * blockDim.x + threadIdx.x;
  if (tid >= 2 * 12288) return;
  int w = tid / 12288;
  int r = tid - w * 12288;
  int k = r / 192;
  int j = r - k * 192;
  const float* W = w ? Whh : Wih;
  float* WT = w ? WThh : WTih;
  WT[k * 192 + j] = W[j * 64 + k];
}

// Fused conv: for each edge e, msg[e,f] = sum_d h[src[e],d] * (Wedge[e,d,f]+b2[d*64+f]);
// agg[dst[e],f] += msg[e,f].  Wedge tiles computed on the fly via MFMA (never stored).
// Block = 64 edges; wave = 16-edge strip; d-loop over the 64 weight rows.
// A (hmid hi/lo) + gathered h rows in LDS; B fragments via pre-packed coalesced
// global loads (L2-resident, no barriers in the d-loop).
__global__ __launch_bounds__(256) void k_conv_fused(
    const u16* __restrict__ Ahi, const u16* __restrict__ Alo,
    const u16* __restrict__ Bph, const u16* __restrict__ Bpl,
    const float* __restrict__ b2, const float* __restrict__ h,
    const int* __restrict__ src, const int* __restrict__ dst,
    float* __restrict__ agg, int E) {
  __shared__ __align__(16) u16 sAh[64 * 136];
  __shared__ __align__(16) u16 sAl[64 * 136];
  __shared__ __align__(16) float hs[64 * 68];
  int m0 = blockIdx.x * 64;
  int tid = threadIdx.x;
#pragma unroll
  for (int p = 0; p < 4; ++p) {
    int slot = p * 256 + tid;        // 1024 slots = 64 rows x 16 segs of 8 u16
    int r = slot >> 4, s = slot & 15;
    int gr = m0 + r;
    if (gr >= E) gr = E - 1;
    *(uint4*)(&sAh[r * 136 + s * 8]) = *(const uint4*)(Ahi + (size_t)gr * 128 + s * 8);
    *(uint4*)(&sAl[r * 136 + s * 8]) = *(const uint4*)(Alo + (size_t)gr * 128 + s * 8);
  }
#pragma unroll
  for (int p = 0; p < 4; ++p) {
    int slot = p * 256 + tid;        // 1024 slots = 64 rows x 16 float4 segs
    int r = slot >> 4, s = slot & 15;
    int ge = m0 + r;
    if (ge >= E) ge = E - 1;
    int sn = src[ge];
    *(float4*)(&hs[r * 68 + s * 4]) = *(const float4*)(h + (size_t)sn * 64 + s * 4);
  }
  __syncthreads();
  int wave = tid >> 6, lane = tid & 63;
  int c = lane & 15, q = lane >> 4;
  float msg[4][4];
#pragma unroll
  for (int nt = 0; nt < 4; ++nt)
#pragma unroll
    for (int r = 0; r < 4; ++r) msg[nt][r] = 0.0f;

  for (int d = 0; d < 64; ++d) {
    float4v acc[4];
#pragma unroll
    for (int nt = 0; nt < 4; ++nt) acc[nt] = (float4v){0.f, 0.f, 0.f, 0.f};
#pragma unroll
    for (int ks = 0; ks < 4; ++ks) {
      int koff = ks * 32 + q * 8;
      short8v ah = *(const short8v*)(&sAh[(wave * 16 + c) * 136 + koff]);
      short8v al = *(const short8v*)(&sAl[(wave * 16 + c) * 136 + koff]);
      size_t bbase = ((size_t)(d * 4 + ks) * 4) * 512 + lane * 8;
#pragma unroll
      for (int nt = 0; nt < 4; ++nt) {
        short8v bh = *(const short8v*)(Bph + bbase + nt * 512);
        short8v bl = *(const short8v*)(Bpl + bbase + nt * 512);
        acc[nt] = __builtin_amdgcn_mfma_f32_16x16x32_bf16(ah, bh, acc[nt], 0, 0, 0);
        acc[nt] = __builtin_amdgcn_mfma_f32_16x16x32_bf16(al, bh, acc[nt], 0, 0, 0);
        acc[nt] = __builtin_amdgcn_mfma_f32_16x16x32_bf16(ah, bl, acc[nt], 0, 0, 0);
      }
    }
    float hd[4];
#pragma unroll
    for (int r = 0; r < 4; ++r) hd[r] = hs[(wave * 16 + q * 4 + r) * 68 + d];
#pragma unroll
    for (int nt = 0; nt < 4; ++nt) {
      float b2v = b2[d * 64 + nt * 16 + c];
#pragma unroll
      for (int r = 0; r < 4; ++r) msg[nt][r] += hd[r] * (acc[nt][r] + b2v);
    }
  }
#pragma unroll
  for (int r = 0; r < 4; ++r) {
    int e = m0 + wave * 16 + q * 4 + r;
    if (e < E) {
      int dn = dst[e];
      float* ap = agg + (size_t)dn * 64 + c;
#pragma unroll
      for (int nt = 0; nt < 4; ++nt) atomicAdd(ap + nt * 16, msg[nt][r]);
    }
  }
}

// GRU: wave-per-node, shuffle-broadcast, coalesced transposed weights   [verified r7/r8]
__global__ __launch_bounds__(256) void k_gru(
    const float* __restrict__ agg, const int* __restrict__ cnt,
    const float* __restrict__ cb, const float* __restrict__ WTih,
    const float* __restrict__ WThh, const float* __restrict__ bih,
    const float* __restrict__ bhh, const float* __restrict__ hin,
    float* __restrict__ hout, int N) {
  int tid = blockIdx.x * blockDim.x + threadIdx.x;
  if (tid >= N * 64) return;
  int n = tid >> 6, f = tid & 63;
  float cf = fmaxf((float)cnt[n], 1.0f);
  float m = fmaxf(agg[(size_t)n * 64 + f] / cf + cb[f], 0.0f);
  float hv = hin[(size_t)n * 64 + f];
  float ir = bih[f], iz = bih[64 + f], in2 = bih[128 + f];
  float hr = bhh[f], hz = bhh[64 + f], hn = bhh[128 + f];
#pragma unroll 4
  for (int k = 0; k < 64; ++k) {
    float mk = __shfl(m, k);
    float hk = __shfl(hv, k);
    const float* wi = WTih + k * 192;
    const float* wh = WThh + k * 192;
    ir += mk * wi[f];
    iz += mk * wi[64 + f];
    in2 += mk * wi[128 + f];
    hr += hk * wh[f];
    hz += hk * wh[64 + f];
    hn += hk * wh[128 + f];
  }
  float r = sigm(ir + hr);
  float z = sigm(iz + hz);
  float ng = tanhf(in2 + r * hn);
  hout[tid] = (1.0f - z) * ng + z * hv;
}

// final MLP   [verified r5-r8]
__global__ void k_final(const float* __restrict__ h, const float* __restrict__ ea3,
                        const int* __restrict__ idx3, const float* __restrict__ Wl1,
                        const float* __restrict__ bl1, const float* __restrict__ Wl2,
                        const float* __restrict__ bl2, float* __restrict__ out, int E3) {
  int e = blockIdx.x * blockDim.x + threadIdx.x;
  if (e >= E3) return;
  int a = idx3[e], b = idx3[E3 + e];
  float feat[72];
  for (int t = 0; t < 64; ++t)
    feat[t] = 0.5f * (h[(size_t)a * 64 + t] + h[(size_t)b * 64 + t]);
  for (int j = 0; j < 8; ++j) feat[64 + j] = ea3[(size_t)e * 8 + j];
  float o = bl2[0];
  for (int t = 0; t < 128; ++t) {
    float acc = bl1[t];
    for (int k = 0; k < 72; ++k) acc += feat[k] * Wl1[k * 128 + t];
    o += fmaxf(acc, 0.0f) * Wl2[t];
  }
  out[e] = o;
}

extern "C" void kernel_launch(void* const* d_in, const int* in_sizes, int n_in,
                              void* d_out, int out_size, void* d_ws, size_t ws_size,
                              hipStream_t stream) {
  const float* x          = (const float*)d_in[0];
  const float* edge_attr  = (const float*)d_in[1];
  const float* edge_attr3 = (const float*)d_in[2];
  const int*   edge_index = (const int*)d_in[3];
  const int*   edge_index3= (const int*)d_in[4];
  const float* W_node = (const float*)d_in[5];
  const float* b_node = (const float*)d_in[6];
  const float* W_ea   = (const float*)d_in[7];
  const float* b_ea   = (const float*)d_in[8];
  const float* W_e1   = (const float*)d_in[9];
  const float* b_e1   = (const float*)d_in[10];
  const float* W_e2   = (const float*)d_in[11];
  const float* b_e2   = (const float*)d_in[12];
  const float* conv_bias = (const float*)d_in[13];
  const float* W_ih   = (const float*)d_in[14];
  const float* b_ih   = (const float*)d_in[15];
  const float* W_hh   = (const float*)d_in[16];
  const float* b_hh   = (const float*)d_in[17];
  const float* W_l1   = (const float*)d_in[18];
  const float* b_l1   = (const float*)d_in[19];
  const float* W_l2   = (const float*)d_in[20];
  const float* b_l2   = (const float*)d_in[21];

  int N  = in_sizes[0] / 8;
  int E  = in_sizes[1] / 19;
  int E3 = in_sizes[2] / 8;

  char* p = (char*)d_ws;
  auto carve = [&](size_t bytes) -> void* {
    char* q = p;
    p += (bytes + 255) & ~(size_t)255;
    return (void*)q;
  };
  float* hA   = (float*)carve((size_t)N * 64 * 4);
  float* hB   = (float*)carve((size_t)N * 64 * 4);
  float* agg  = (float*)carve((size_t)N * 64 * 4);
  int*   cnt  = (int*)carve((size_t)N * 4);
  u16*   Ahi  = (u16*)carve((size_t)E * 128 * 2);
  u16*   Alo  = (u16*)carve((size_t)E * 128 * 2);
  u16*   Bph  = (u16*)carve((size_t)128 * 4096 * 2);
  u16*   Bpl  = (u16*)carve((size_t)128 * 4096 * 2);
  float* WTih = (float*)carve(12288 * 4);
  float* WThh = (float*)carve(12288 * 4);
  // total ~47 MB — far below workspace (>=400 MB per r7/r8 chunk arithmetic)

  const int* src = edge_index;
  const int* dst = edge_index + E;

  k_zero_i<<<(N + 255) / 256, 256, 0, stream>>>(cnt, N);
  k_cnt<<<(E + 255) / 256, 256, 0, stream>>>(dst, cnt, E);
  k_node<<<((size_t)N * 64 + 255) / 256, 256, 0, stream>>>(x, W_node, b_node, hA, N);
  k_edge_mlp<<<((size_t)E * 128 + 255) / 256, 256, 0, stream>>>(edge_attr, W_ea, b_ea,
                                                                W_e1, b_e1, Ahi, Alo, E);
  k_pack_b<<<(128 * 4096 + 255) / 256, 256, 0, stream>>>(W_e2, Bph, Bpl);
  k_prep_wt<<<(2 * 12288 + 255) / 256, 256, 0, stream>>>(W_ih, W_hh, WTih, WThh);

  float* hcur = hA;
  float* hnxt = hB;
  int nconv = (E + 63) / 64;
  for (int it = 0; it < 3; ++it) {
    k_zero_f<<<((size_t)N * 64 + 255) / 256, 256, 0, stream>>>(agg, N * 64);
    k_conv_fused<<<nconv, 256, 0, stream>>>(Ahi, Alo, Bph, Bpl, b_e2, hcur, src, dst, agg, E);
    k_gru<<<((size_t)N * 64 + 255) / 256, 256, 0, stream>>>(agg, cnt, conv_bias, WTih, WThh,
                                                            b_ih, b_hh, hcur, hnxt, N);
    float* tmp = hcur; hcur = hnxt; hnxt = tmp;
  }
  k_final<<<(E3 + 255) / 256, 256, 0, stream>>>(hcur, edge_attr3, edge_index3, W_l1, b_l1,
                                                W_l2, b_l2, (float*)d_out, E3);
}

// Round 10
// 821.517 us; speedup vs baseline: 24.6331x; 1.6087x over previous
//
#include <hip/hip_runtime.h>

typedef unsigned short u16;
typedef unsigned int u32;
typedef __attribute__((ext_vector_type(8))) short short8v;
typedef __attribute__((ext_vector_type(4))) float float4v;

__device__ __forceinline__ float sigm(float x) { return 1.0f / (1.0f + expf(-x)); }
__device__ __forceinline__ u16 f2bf(float f) {
  u32 u = __float_as_uint(f);
  u32 r = (u + 0x7fffu + ((u >> 16) & 1u)) >> 16;
  return (u16)r;
}
__device__ __forceinline__ float bf2f(u16 w) { return __uint_as_float(((u32)w) << 16); }

__global__ void k_zero_f(float* __restrict__ p, int n) {
  int i = blockIdx.x * blockDim.x + threadIdx.x;
  if (i < n) p[i] = 0.0f;
}
__global__ void k_zero_i(int* __restrict__ p, int n) {
  int i = blockIdx.x * blockDim.x + threadIdx.x;
  if (i < n) p[i] = 0;
}

__global__ void k_cnt(const int* __restrict__ dst, int* __restrict__ cnt, int E) {
  int e = blockIdx.x * blockDim.x + threadIdx.x;
  if (e < E) atomicAdd(&cnt[dst[e]], 1);
}

// h[n,f] = relu(sum_k x[n,k] * W_node[k,f] + b_node[f])   [verified r5-r9]
__global__ void k_node(const float* __restrict__ x, const float* __restrict__ Wn,
                       const float* __restrict__ bn, float* __restrict__ h, int N) {
  int tid = blockIdx.x * blockDim.x + threadIdx.x;
  if (tid >= N * 64) return;
  int n = tid >> 6, f = tid & 63;
  float acc = bn[f];
  for (int k = 0; k < 8; ++k) acc += x[(size_t)n * 8 + k] * Wn[k * 64 + f];
  h[tid] = fmaxf(acc, 0.0f);
}

// hmid = relu(relu(ea@Wea+bea)@We1+be1), fused bf16 hi/lo split output   [verified r8/r9]
__global__ void k_edge_mlp(const float* __restrict__ ea_in, const float* __restrict__ Wea,
                           const float* __restrict__ bea, const float* __restrict__ We1,
                           const float* __restrict__ be1, u16* __restrict__ Ahi,
                           u16* __restrict__ Alo, int E) {
  int tid = blockIdx.x * blockDim.x + threadIdx.x;
  if (tid >= E * 128) return;
  int e = tid >> 7, t = tid & 127;
  const float* att = ea_in + (size_t)e * 19;
  float ea[12];
  for (int j = 0; j < 12; ++j) {
    float a = bea[j];
    for (int k = 0; k < 19; ++k) a += att[k] * Wea[k * 12 + j];
    ea[j] = fmaxf(a, 0.0f);
  }
  float a = be1[t];
  for (int j = 0; j < 12; ++j) a += ea[j] * We1[j * 128 + t];
  float v = fmaxf(a, 0.0f);
  u16 hi = f2bf(v);
  Ahi[tid] = hi;
  Alo[tid] = f2bf(v - bf2f(hi));
}

// Pack W_e2 into MFMA-fragment-ordered bf16 (hi only; B is bf16-grade):
// Bp[(((d*4+ks)*4+nt)*64 + lane)*8 + j] = bf16(W_e2[k][n]),
//   k = ks*32 + (lane>>4)*8 + j,  n = d*64 + nt*16 + (lane&15)   [layout verified r9]
__global__ void k_pack_b(const float* __restrict__ W2, u16* __restrict__ Bph) {
  int tid = blockIdx.x * blockDim.x + threadIdx.x;
  if (tid >= 128 * 4096) return;
  int j = tid & 7;
  int lane = (tid >> 3) & 63;
  int nt = (tid >> 9) & 3;
  int ks = (tid >> 11) & 3;
  int d = tid >> 13;
  int c = lane & 15, q = lane >> 4;
  int k = ks * 32 + q * 8 + j;
  int n = d * 64 + nt * 16 + c;
  Bph[tid] = f2bf(W2[(size_t)k * 4096 + n]);
}

// WT[k*192 + j] = W[j*64 + k]   [verified r7-r9]
__global__ void k_prep_wt(const float* __restrict__ Wih, const float* __restrict__ Whh,
                          float* __restrict__ WTih, float* __restrict__ WThh) {
  int tid = blockIdx.x * blockDim.x + threadIdx.x;
  if (tid >= 2 * 12288) return;
  int w = tid / 12288;
  int r = tid - w * 12288;
  int k = r / 192;
  int j = r - k * 192;
  const float* W = w ? Whh : Wih;
  float* WT = w ? WThh : WTih;
  WT[k * 192 + j] = W[j * 64 + k];
}

// Fused conv: msg[e,f] = sum_d h[src[e],d] * (Wedge[e,d,f]+b2[d*64+f]);
// agg[dst[e],f] += msg[e,f].  Wedge tiles computed on the fly (never stored).
// Block = 64 edges x 32 d-values (blockIdx.y selects d half). B fragments
// register-double-buffered across d (compute waits only the older batch).
__global__ __launch_bounds__(256, 2) void k_conv_fused(
    const u16* __restrict__ Ahi, const u16* __restrict__ Alo,
    const u16* __restrict__ Bph, const float* __restrict__ b2,
    const float* __restrict__ h, const int* __restrict__ src,
    const int* __restrict__ dst, float* __restrict__ agg, int E) {
  __shared__ __align__(16) u16 sAh[64 * 136];
  __shared__ __align__(16) u16 sAl[64 * 136];
  __shared__ __align__(16) float hs[64 * 36];
  __shared__ __align__(16) float sb2[2048];
  int m0 = blockIdx.x * 64;
  int d0 = blockIdx.y * 32;
  int tid = threadIdx.x;
#pragma unroll
  for (int p = 0; p < 4; ++p) {
    int slot = p * 256 + tid;        // 1024 slots = 64 rows x 16 segs of 8 u16
    int r = slot >> 4, s = slot & 15;
    int gr = m0 + r;
    if (gr >= E) gr = E - 1;
    *(uint4*)(&sAh[r * 136 + s * 8]) = *(const uint4*)(Ahi + (size_t)gr * 128 + s * 8);
    *(uint4*)(&sAl[r * 136 + s * 8]) = *(const uint4*)(Alo + (size_t)gr * 128 + s * 8);
  }
#pragma unroll
  for (int p = 0; p < 2; ++p) {
    int slot = p * 256 + tid;        // 512 slots = 64 rows x 8 float4 (32 d-vals)
    int r = slot >> 3, s = slot & 7;
    int ge = m0 + r;
    if (ge >= E) ge = E - 1;
    int sn = src[ge];
    *(float4*)(&hs[r * 36 + s * 4]) = *(const float4*)(h + (size_t)sn * 64 + d0 + s * 4);
  }
#pragma unroll
  for (int p = 0; p < 2; ++p) {
    int slot = p * 256 + tid;        // 512 float4 = 2048 floats of b2 slice
    *(float4*)(&sb2[slot * 4]) = *(const float4*)(b2 + d0 * 64 + slot * 4);
  }
  __syncthreads();
  int wave = tid >> 6, lane = tid & 63;
  int c = lane & 15, q = lane >> 4;
  float msg[4][4];
#pragma unroll
  for (int nt = 0; nt < 4; ++nt)
#pragma unroll
    for (int r = 0; r < 4; ++r) msg[nt][r] = 0.0f;

  short8v bufA[16], bufB[16];
  auto loadB = [&](int dd, short8v* buf) {
    const u16* bp = Bph + (size_t)dd * 8192 + lane * 8;
#pragma unroll
    for (int i = 0; i < 16; ++i) buf[i] = *(const short8v*)(bp + i * 512);
  };
  auto compute = [&](int dd, const short8v* buf) {
    float4v acc[4];
#pragma unroll
    for (int nt = 0; nt < 4; ++nt) acc[nt] = (float4v){0.f, 0.f, 0.f, 0.f};
#pragma unroll
    for (int ks = 0; ks < 4; ++ks) {
      int koff = ks * 32 + q * 8;
      short8v ah = *(const short8v*)(&sAh[(wave * 16 + c) * 136 + koff]);
      short8v al = *(const short8v*)(&sAl[(wave * 16 + c) * 136 + koff]);
#pragma unroll
      for (int nt = 0; nt < 4; ++nt) {
        acc[nt] = __builtin_amdgcn_mfma_f32_16x16x32_bf16(ah, buf[ks * 4 + nt], acc[nt], 0, 0, 0);
        acc[nt] = __builtin_amdgcn_mfma_f32_16x16x32_bf16(al, buf[ks * 4 + nt], acc[nt], 0, 0, 0);
      }
    }
    int dl = dd - d0;
    float hd[4];
#pragma unroll
    for (int r = 0; r < 4; ++r) hd[r] = hs[(wave * 16 + q * 4 + r) * 36 + dl];
#pragma unroll
    for (int nt = 0; nt < 4; ++nt) {
      float b2v = sb2[dl * 64 + nt * 16 + c];
#pragma unroll
      for (int r = 0; r < 4; ++r) msg[nt][r] += hd[r] * (acc[nt][r] + b2v);
    }
  };

  loadB(d0, bufA);
  for (int d = d0; d < d0 + 32; d += 2) {
    loadB(d + 1, bufB);
    compute(d, bufA);
    if (d + 2 < d0 + 32) loadB(d + 2, bufA);
    compute(d + 1, bufB);
  }
#pragma unroll
  for (int r = 0; r < 4; ++r) {
    int e = m0 + wave * 16 + q * 4 + r;
    if (e < E) {
      int dn = dst[e];
      float* ap = agg + (size_t)dn * 64 + c;
#pragma unroll
      for (int nt = 0; nt < 4; ++nt) atomicAdd(ap + nt * 16, msg[nt][r]);
    }
  }
}

// GRU: wave-per-node, shuffle-broadcast, coalesced transposed weights   [verified r7-r9]
__global__ __launch_bounds__(256) void k_gru(
    const float* __restrict__ agg, const int* __restrict__ cnt,
    const float* __restrict__ cb, const float* __restrict__ WTih,
    const float* __restrict__ WThh, const float* __restrict__ bih,
    const float* __restrict__ bhh, const float* __restrict__ hin,
    float* __restrict__ hout, int N) {
  int tid = blockIdx.x * blockDim.x + threadIdx.x;
  if (tid >= N * 64) return;
  int n = tid >> 6, f = tid & 63;
  float cf = fmaxf((float)cnt[n], 1.0f);
  float m = fmaxf(agg[(size_t)n * 64 + f] / cf + cb[f], 0.0f);
  float hv = hin[(size_t)n * 64 + f];
  float ir = bih[f], iz = bih[64 + f], in2 = bih[128 + f];
  float hr = bhh[f], hz = bhh[64 + f], hn = bhh[128 + f];
#pragma unroll 4
  for (int k = 0; k < 64; ++k) {
    float mk = __shfl(m, k);
    float hk = __shfl(hv, k);
    const float* wi = WTih + k * 192;
    const float* wh = WThh + k * 192;
    ir += mk * wi[f];
    iz += mk * wi[64 + f];
    in2 += mk * wi[128 + f];
    hr += hk * wh[f];
    hz += hk * wh[64 + f];
    hn += hk * wh[128 + f];
  }
  float r = sigm(ir + hr);
  float z = sigm(iz + hz);
  float ng = tanhf(in2 + r * hn);
  hout[tid] = (1.0f - z) * ng + z * hv;
}

// final MLP   [verified r5-r9]
__global__ void k_final(const float* __restrict__ h, const float* __restrict__ ea3,
                        const int* __restrict__ idx3, const float* __restrict__ Wl1,
                        const float* __restrict__ bl1, const float* __restrict__ Wl2,
                        const float* __restrict__ bl2, float* __restrict__ out, int E3) {
  int e = blockIdx.x * blockDim.x + threadIdx.x;
  if (e >= E3) return;
  int a = idx3[e], b = idx3[E3 + e];
  float feat[72];
  for (int t = 0; t < 64; ++t)
    feat[t] = 0.5f * (h[(size_t)a * 64 + t] + h[(size_t)b * 64 + t]);
  for (int j = 0; j < 8; ++j) feat[64 + j] = ea3[(size_t)e * 8 + j];
  float o = bl2[0];
  for (int t = 0; t < 128; ++t) {
    float acc = bl1[t];
    for (int k = 0; k < 72; ++k) acc += feat[k] * Wl1[k * 128 + t];
    o += fmaxf(acc, 0.0f) * Wl2[t];
  }
  out[e] = o;
}

extern "C" void kernel_launch(void* const* d_in, const int* in_sizes, int n_in,
                              void* d_out, int out_size, void* d_ws, size_t ws_size,
                              hipStream_t stream) {
  const float* x          = (const float*)d_in[0];
  const float* edge_attr  = (const float*)d_in[1];
  const float* edge_attr3 = (const float*)d_in[2];
  const int*   edge_index = (const int*)d_in[3];
  const int*   edge_index3= (const int*)d_in[4];
  const float* W_node = (const float*)d_in[5];
  const float* b_node = (const float*)d_in[6];
  const float* W_ea   = (const float*)d_in[7];
  const float* b_ea   = (const float*)d_in[8];
  const float* W_e1   = (const float*)d_in[9];
  const float* b_e1   = (const float*)d_in[10];
  const float* W_e2   = (const float*)d_in[11];
  const float* b_e2   = (const float*)d_in[12];
  const float* conv_bias = (const float*)d_in[13];
  const float* W_ih   = (const float*)d_in[14];
  const float* b_ih   = (const float*)d_in[15];
  const float* W_hh   = (const float*)d_in[16];
  const float* b_hh   = (const float*)d_in[17];
  const float* W_l1   = (const float*)d_in[18];
  const float* b_l1   = (const float*)d_in[19];
  const float* W_l2   = (const float*)d_in[20];
  const float* b_l2   = (const float*)d_in[21];

  int N  = in_sizes[0] / 8;
  int E  = in_sizes[1] / 19;
  int E3 = in_sizes[2] / 8;

  char* p = (char*)d_ws;
  auto carve = [&](size_t bytes) -> void* {
    char* q = p;
    p += (bytes + 255) & ~(size_t)255;
    return (void*)q;
  };
  float* hA   = (float*)carve((size_t)N * 64 * 4);
  float* hB   = (float*)carve((size_t)N * 64 * 4);
  float* agg  = (float*)carve((size_t)N * 64 * 4);
  int*   cnt  = (int*)carve((size_t)N * 4);
  u16*   Ahi  = (u16*)carve((size_t)E * 128 * 2);
  u16*   Alo  = (u16*)carve((size_t)E * 128 * 2);
  u16*   Bph  = (u16*)carve((size_t)128 * 4096 * 2);
  float* WTih = (float*)carve(12288 * 4);
  float* WThh = (float*)carve(12288 * 4);

  const int* src = edge_index;
  const int* dst = edge_index + E;

  k_zero_i<<<(N + 255) / 256, 256, 0, stream>>>(cnt, N);
  k_cnt<<<(E + 255) / 256, 256, 0, stream>>>(dst, cnt, E);
  k_node<<<((size_t)N * 64 + 255) / 256, 256, 0, stream>>>(x, W_node, b_node, hA, N);
  k_edge_mlp<<<((size_t)E * 128 + 255) / 256, 256, 0, stream>>>(edge_attr, W_ea, b_ea,
                                                                W_e1, b_e1, Ahi, Alo, E);
  k_pack_b<<<(128 * 4096 + 255) / 256, 256, 0, stream>>>(W_e2, Bph);
  k_prep_wt<<<(2 * 12288 + 255) / 256, 256, 0, stream>>>(W_ih, W_hh, WTih, WThh);

  float* hcur = hA;
  float* hnxt = hB;
  dim3 gconv((E + 63) / 64, 2);
  for (int it = 0; it < 3; ++it) {
    k_zero_f<<<((size_t)N * 64 + 255) / 256, 256, 0, stream>>>(agg, N * 64);
    k_conv_fused<<<gconv, 256, 0, stream>>>(Ahi, Alo, Bph, b_e2, hcur, src, dst, agg, E);
    k_gru<<<((size_t)N * 64 + 255) / 256, 256, 0, stream>>>(agg, cnt, conv_bias, WTih, WThh,
                                                            b_ih, b_hh, hcur, hnxt, N);
    float* tmp = hcur; hcur = hnxt; hnxt = tmp;
  }
  k_final<<<(E3 + 255) / 256, 256, 0, stream>>>(hcur, edge_attr3, edge_index3, W_l1, b_l1,
                                                W_l2, b_l2, (float*)d_out, E3);
}

// Round 11
// 815.047 us; speedup vs baseline: 24.8287x; 1.0079x over previous
//
#include <hip/hip_runtime.h>

typedef unsigned short u16;
typedef unsigned int u32;
typedef __attribute__((ext_vector_type(8))) short short8v;
typedef __attribute__((ext_vector_type(4))) float float4v;

__device__ __forceinline__ float sigm(float x) { return 1.0f / (1.0f + expf(-x)); }
__device__ __forceinline__ u16 f2bf(float f) {
  u32 u = __float_as_uint(f);
  u32 r = (u + 0x7fffu + ((u >> 16) & 1u)) >> 16;
  return (u16)r;
}
__device__ __forceinline__ float bf2f(u16 w) { return __uint_as_float(((u32)w) << 16); }

__global__ void k_zero_f(float* __restrict__ p, int n) {
  int i = blockIdx.x * blockDim.x + threadIdx.x;
  if (i < n) p[i] = 0.0f;
}
__global__ void k_zero_i(int* __restrict__ p, int n) {
  int i = blockIdx.x * blockDim.x + threadIdx.x;
  if (i < n) p[i] = 0;
}

__global__ void k_cnt(const int* __restrict__ dst, int* __restrict__ cnt, int E) {
  int e = blockIdx.x * blockDim.x + threadIdx.x;
  if (e < E) atomicAdd(&cnt[dst[e]], 1);
}

// h[n,f] = relu(sum_k x[n,k] * W_node[k,f] + b_node[f])   [verified r5-r10]
__global__ void k_node(const float* __restrict__ x, const float* __restrict__ Wn,
                       const float* __restrict__ bn, float* __restrict__ h, int N) {
  int tid = blockIdx.x * blockDim.x + threadIdx.x;
  if (tid >= N * 64) return;
  int n = tid >> 6, f = tid & 63;
  float acc = bn[f];
  for (int k = 0; k < 8; ++k) acc += x[(size_t)n * 8 + k] * Wn[k * 64 + f];
  h[tid] = fmaxf(acc, 0.0f);
}

// hmid = relu(relu(ea@Wea+bea)@We1+be1), fused bf16 hi/lo split output   [verified r8-r10]
__global__ void k_edge_mlp(const float* __restrict__ ea_in, const float* __restrict__ Wea,
                           const float* __restrict__ bea, const float* __restrict__ We1,
                           const float* __restrict__ be1, u16* __restrict__ Ahi,
                           u16* __restrict__ Alo, int E) {
  int tid = blockIdx.x * blockDim.x + threadIdx.x;
  if (tid >= E * 128) return;
  int e = tid >> 7, t = tid & 127;
  const float* att = ea_in + (size_t)e * 19;
  float ea[12];
  for (int j = 0; j < 12; ++j) {
    float a = bea[j];
    for (int k = 0; k < 19; ++k) a += att[k] * Wea[k * 12 + j];
    ea[j] = fmaxf(a, 0.0f);
  }
  float a = be1[t];
  for (int j = 0; j < 12; ++j) a += ea[j] * We1[j * 128 + t];
  float v = fmaxf(a, 0.0f);
  u16 hi = f2bf(v);
  Ahi[tid] = hi;
  Alo[tid] = f2bf(v - bf2f(hi));
}

// Pack W_e2 into MFMA-fragment-ordered bf16:
// Bp[(((d*4+ks)*4+nt)*64 + lane)*8 + j] = bf16(W_e2[k][n]),
//   k = ks*32 + (lane>>4)*8 + j,  n = d*64 + nt*16 + (lane&15)   [verified r9/r10]
__global__ void k_pack_b(const float* __restrict__ W2, u16* __restrict__ Bph) {
  int tid = blockIdx.x * blockDim.x + threadIdx.x;
  if (tid >= 128 * 4096) return;
  int j = tid & 7;
  int lane = (tid >> 3) & 63;
  int nt = (tid >> 9) & 3;
  int ks = (tid >> 11) & 3;
  int d = tid >> 13;
  int c = lane & 15, q = lane >> 4;
  int k = ks * 32 + q * 8 + j;
  int n = d * 64 + nt * 16 + c;
  Bph[tid] = f2bf(W2[(size_t)k * 4096 + n]);
}

// GRU weights: WT16[k*192 + j] = bf16(W[j*64 + k])  (bf16-packed transposed layout)
__global__ void k_prep_wt(const float* __restrict__ Wih, const float* __restrict__ Whh,
                          u16* __restrict__ WTih, u16* __restrict__ WThh) {
  int tid = blockIdx.x * blockDim.x + threadIdx.x;
  if (tid >= 2 * 12288) return;
  int w = tid / 12288;
  int r = tid - w * 12288;
  int k = r / 192;
  int j = r - k * 192;
  const float* W = w ? Whh : Wih;
  u16* WT = w ? WThh : WTih;
  WT[k * 192 + j] = f2bf(W[j * 64 + k]);
}

// Fused conv: msg[e,f] = sum_d h[src[e],d] * (Wedge[e,d,f]+b2[d*64+f]);
// agg[dst[e],f] += msg[e,f].  Wedge tiles computed on the fly (never stored).
// Block = 64 edges x 32 d-values. A fragments hoisted to registers (d-invariant);
// B fragments register-double-buffered across d.
__global__ __launch_bounds__(256, 2) void k_conv_fused(
    const u16* __restrict__ Ahi, const u16* __restrict__ Alo,
    const u16* __restrict__ Bph, const float* __restrict__ b2,
    const float* __restrict__ h, const int* __restrict__ src,
    const int* __restrict__ dst, float* __restrict__ agg, int E) {
  __shared__ __align__(16) u16 sAh[64 * 136];
  __shared__ __align__(16) u16 sAl[64 * 136];
  __shared__ __align__(16) float hs[64 * 36];
  __shared__ __align__(16) float sb2[2048];
  int m0 = blockIdx.x * 64;
  int d0 = blockIdx.y * 32;
  int tid = threadIdx.x;
#pragma unroll
  for (int p = 0; p < 4; ++p) {
    int slot = p * 256 + tid;        // 1024 slots = 64 rows x 16 segs of 8 u16
    int r = slot >> 4, s = slot & 15;
    int gr = m0 + r;
    if (gr >= E) gr = E - 1;
    *(uint4*)(&sAh[r * 136 + s * 8]) = *(const uint4*)(Ahi + (size_t)gr * 128 + s * 8);
    *(uint4*)(&sAl[r * 136 + s * 8]) = *(const uint4*)(Alo + (size_t)gr * 128 + s * 8);
  }
#pragma unroll
  for (int p = 0; p < 2; ++p) {
    int slot = p * 256 + tid;        // 512 slots = 64 rows x 8 float4 (32 d-vals)
    int r = slot >> 3, s = slot & 7;
    int ge = m0 + r;
    if (ge >= E) ge = E - 1;
    int sn = src[ge];
    *(float4*)(&hs[r * 36 + s * 4]) = *(const float4*)(h + (size_t)sn * 64 + d0 + s * 4);
  }
#pragma unroll
  for (int p = 0; p < 2; ++p) {
    int slot = p * 256 + tid;        // 512 float4 = 2048 floats of b2 slice
    *(float4*)(&sb2[slot * 4]) = *(const float4*)(b2 + d0 * 64 + slot * 4);
  }
  __syncthreads();
  int wave = tid >> 6, lane = tid & 63;
  int c = lane & 15, q = lane >> 4;
  // Hoist d-invariant A fragments into registers (8 x short8v = 32 VGPRs).
  short8v ah[4], al[4];
#pragma unroll
  for (int ks = 0; ks < 4; ++ks) {
    int koff = ks * 32 + q * 8;
    ah[ks] = *(const short8v*)(&sAh[(wave * 16 + c) * 136 + koff]);
    al[ks] = *(const short8v*)(&sAl[(wave * 16 + c) * 136 + koff]);
  }
  float msg[4][4];
#pragma unroll
  for (int nt = 0; nt < 4; ++nt)
#pragma unroll
    for (int r = 0; r < 4; ++r) msg[nt][r] = 0.0f;

  short8v bufA[16], bufB[16];
  auto loadB = [&](int dd, short8v* buf) {
    const u16* bp = Bph + (size_t)dd * 8192 + lane * 8;
#pragma unroll
    for (int i = 0; i < 16; ++i) buf[i] = *(const short8v*)(bp + i * 512);
  };
  auto compute = [&](int dd, const short8v* buf) {
    float4v acc[4];
#pragma unroll
    for (int nt = 0; nt < 4; ++nt) acc[nt] = (float4v){0.f, 0.f, 0.f, 0.f};
#pragma unroll
    for (int ks = 0; ks < 4; ++ks) {
#pragma unroll
      for (int nt = 0; nt < 4; ++nt) {
        acc[nt] = __builtin_amdgcn_mfma_f32_16x16x32_bf16(ah[ks], buf[ks * 4 + nt], acc[nt], 0, 0, 0);
        acc[nt] = __builtin_amdgcn_mfma_f32_16x16x32_bf16(al[ks], buf[ks * 4 + nt], acc[nt], 0, 0, 0);
      }
    }
    int dl = dd - d0;
    float hd[4];
#pragma unroll
    for (int r = 0; r < 4; ++r) hd[r] = hs[(wave * 16 + q * 4 + r) * 36 + dl];
#pragma unroll
    for (int nt = 0; nt < 4; ++nt) {
      float b2v = sb2[dl * 64 + nt * 16 + c];
#pragma unroll
      for (int r = 0; r < 4; ++r) msg[nt][r] += hd[r] * (acc[nt][r] + b2v);
    }
  };

  loadB(d0, bufA);
  for (int d = d0; d < d0 + 32; d += 2) {
    loadB(d + 1, bufB);
    compute(d, bufA);
    if (d + 2 < d0 + 32) loadB(d + 2, bufA);
    compute(d + 1, bufB);
  }
#pragma unroll
  for (int r = 0; r < 4; ++r) {
    int e = m0 + wave * 16 + q * 4 + r;
    if (e < E) {
      int dn = dst[e];
      float* ap = agg + (size_t)dn * 64 + c;
#pragma unroll
      for (int nt = 0; nt < 4; ++nt) atomicAdd(ap + nt * 16, msg[nt][r]);
    }
  }
}

// GRU: wave-per-node, shuffle-broadcast, coalesced bf16 transposed weights.
__global__ __launch_bounds__(256) void k_gru(
    const float* __restrict__ agg, const int* __restrict__ cnt,
    const float* __restrict__ cb, const u16* __restrict__ WTih,
    const u16* __restrict__ WThh, const float* __restrict__ bih,
    const float* __restrict__ bhh, const float* __restrict__ hin,
    float* __restrict__ hout, int N) {
  int tid = blockIdx.x * blockDim.x + threadIdx.x;
  if (tid >= N * 64) return;
  int n = tid >> 6, f = tid & 63;
  float cf = fmaxf((float)cnt[n], 1.0f);
  float m = fmaxf(agg[(size_t)n * 64 + f] / cf + cb[f], 0.0f);
  float hv = hin[(size_t)n * 64 + f];
  float ir = bih[f], iz = bih[64 + f], in2 = bih[128 + f];
  float hr = bhh[f], hz = bhh[64 + f], hn = bhh[128 + f];
#pragma unroll 4
  for (int k = 0; k < 64; ++k) {
    float mk = __shfl(m, k);
    float hk = __shfl(hv, k);
    const u16* wi = WTih + k * 192;
    const u16* wh = WThh + k * 192;
    ir += mk * bf2f(wi[f]);
    iz += mk * bf2f(wi[64 + f]);
    in2 += mk * bf2f(wi[128 + f]);
    hr += hk * bf2f(wh[f]);
    hz += hk * bf2f(wh[64 + f]);
    hn += hk * bf2f(wh[128 + f]);
  }
  float r = sigm(ir + hr);
  float z = sigm(iz + hz);
  float ng = tanhf(in2 + r * hn);
  hout[tid] = (1.0f - z) * ng + z * hv;
}

// final MLP   [verified r5-r10]
__global__ void k_final(const float* __restrict__ h, const float* __restrict__ ea3,
                        const int* __restrict__ idx3, const float* __restrict__ Wl1,
                        const float* __restrict__ bl1, const float* __restrict__ Wl2,
                        const float* __restrict__ bl2, float* __restrict__ out, int E3) {
  int e = blockIdx.x * blockDim.x + threadIdx.x;
  if (e >= E3) return;
  int a = idx3[e], b = idx3[E3 + e];
  float feat[72];
  for (int t = 0; t < 64; ++t)
    feat[t] = 0.5f * (h[(size_t)a * 64 + t] + h[(size_t)b * 64 + t]);
  for (int j = 0; j < 8; ++j) feat[64 + j] = ea3[(size_t)e * 8 + j];
  float o = bl2[0];
  for (int t = 0; t < 128; ++t) {
    float acc = bl1[t];
    for (int k = 0; k < 72; ++k) acc += feat[k] * Wl1[k * 128 + t];
    o += fmaxf(acc, 0.0f) * Wl2[t];
  }
  out[e] = o;
}

extern "C" void kernel_launch(void* const* d_in, const int* in_sizes, int n_in,
                              void* d_out, int out_size, void* d_ws, size_t ws_size,
                              hipStream_t stream) {
  const float* x          = (const float*)d_in[0];
  const float* edge_attr  = (const float*)d_in[1];
  const float* edge_attr3 = (const float*)d_in[2];
  const int*   edge_index = (const int*)d_in[3];
  const int*   edge_index3= (const int*)d_in[4];
  const float* W_node = (const float*)d_in[5];
  const float* b_node = (const float*)d_in[6];
  const float* W_ea   = (const float*)d_in[7];
  const float* b_ea   = (const float*)d_in[8];
  const float* W_e1   = (const float*)d_in[9];
  const float* b_e1   = (const float*)d_in[10];
  const float* W_e2   = (const float*)d_in[11];
  const float* b_e2   = (const float*)d_in[12];
  const float* conv_bias = (const float*)d_in[13];
  const float* W_ih   = (const float*)d_in[14];
  const float* b_ih   = (const float*)d_in[15];
  const float* W_hh   = (const float*)d_in[16];
  const float* b_hh   = (const float*)d_in[17];
  const float* W_l1   = (const float*)d_in[18];
  const float* b_l1   = (const float*)d_in[19];
  const float* W_l2   = (const float*)d_in[20];
  const float* b_l2   = (const float*)d_in[21];

  int N  = in_sizes[0] / 8;
  int E  = in_sizes[1] / 19;
  int E3 = in_sizes[2] / 8;

  char* p = (char*)d_ws;
  auto carve = [&](size_t bytes) -> void* {
    char* q = p;
    p += (bytes + 255) & ~(size_t)255;
    return (void*)q;
  };
  float* hA   = (float*)carve((size_t)N * 64 * 4);
  float* hB   = (float*)carve((size_t)N * 64 * 4);
  float* agg  = (float*)carve((size_t)N * 64 * 4);
  int*   cnt  = (int*)carve((size_t)N * 4);
  u16*   Ahi  = (u16*)carve((size_t)E * 128 * 2);
  u16*   Alo  = (u16*)carve((size_t)E * 128 * 2);
  u16*   Bph  = (u16*)carve((size_t)128 * 4096 * 2);
  u16*   WTih = (u16*)carve(12288 * 2);
  u16*   WThh = (u16*)carve(12288 * 2);

  const int* src = edge_index;
  const int* dst = edge_index + E;

  k_zero_i<<<(N + 255) / 256, 256, 0, stream>>>(cnt, N);
  k_cnt<<<(E + 255) / 256, 256, 0, stream>>>(dst, cnt, E);
  k_node<<<((size_t)N * 64 + 255) / 256, 256, 0, stream>>>(x, W_node, b_node, hA, N);
  k_edge_mlp<<<((size_t)E * 128 + 255) / 256, 256, 0, stream>>>(edge_attr, W_ea, b_ea,
                                                                W_e1, b_e1, Ahi, Alo, E);
  k_pack_b<<<(128 * 4096 + 255) / 256, 256, 0, stream>>>(W_e2, Bph);
  k_prep_wt<<<(2 * 12288 + 255) / 256, 256, 0, stream>>>(W_ih, W_hh, WTih, WThh);

  float* hcur = hA;
  float* hnxt = hB;
  dim3 gconv((E + 63) / 64, 2);
  for (int it = 0; it < 3; ++it) {
    k_zero_f<<<((size_t)N * 64 + 255) / 256, 256, 0, stream>>>(agg, N * 64);
    k_conv_fused<<<gconv, 256, 0, stream>>>(Ahi, Alo, Bph, b_e2, hcur, src, dst, agg, E);
    k_gru<<<((size_t)N * 64 + 255) / 256, 256, 0, stream>>>(agg, cnt, conv_bias, WTih, WThh,
                                                            b_ih, b_hh, hcur, hnxt, N);
    float* tmp = hcur; hcur = hnxt; hnxt = tmp;
  }
  k_final<<<(E3 + 255) / 256, 256, 0, stream>>>(hcur, edge_attr3, edge_index3, W_l1, b_l1,
                                                W_l2, b_l2, (float*)d_out, E3);
}